// Round 11
// baseline (574.911 us; speedup 1.0000x reference)
//
// Ernie4.5 MoE MLP — MI355X gfx950
// R11: m201-style schedule on R8's verified data paths. Both GEMMs: BM=128,
//      BN=256, BK=32, 512thr/8 waves (wave 64x64), 4 LDS buffers (96KB),
//      staging at distance 3, per-step vmcnt(6) (tail 3/0) BEFORE the step
//      barrier, 2 phases/step each {ds_reads; barrier; lgkm0; setprio; 8 MFMA;
//      barrier}. Weights pre-converted bf16 (wcvt x3, R8-verified maps).
// ws peak ~250 MB. eo aliases adisp; wdt aliases wgu (dead after gemm1).
#include <hip/hip_runtime.h>
#include <hip/hip_bf16.h>

constexpr int S_TOK = 16384;
constexpr int HDIM  = 1024;
constexpr int IDIM  = 512;
constexpr int NEXP  = 64;
constexpr int CAPC  = 640;
constexpr int NCHUNK = 128;   // 32768 routing entries / 256

typedef __attribute__((ext_vector_type(8))) short bf16x8;
typedef __attribute__((ext_vector_type(4))) float f32x4;

__device__ __forceinline__ float bf2f(unsigned short u){
  return __uint_as_float(((unsigned)u) << 16);
}
__device__ __forceinline__ unsigned short f2bf(float f){   // RNE bf16 (inputs finite)
  unsigned u = __float_as_uint(f);
  return (unsigned short)((u + 0x7fffu + ((u >> 16) & 1u)) >> 16);
}
__device__ __forceinline__ unsigned pk2(float a, float b){
  return (unsigned)f2bf(a) | ((unsigned)f2bf(b) << 16);
}
__device__ __forceinline__ void gload_lds16(const void* g, void* l){
  __builtin_amdgcn_global_load_lds((const __attribute__((address_space(1))) unsigned*)g,
                                   (__attribute__((address_space(3))) unsigned*)l, 16, 0, 0);
}

// ---------------- weight fp32 [R][C] -> bf16 transposed, column remap --------
// dst row n' = (gc>>4)*ostep + (gc&15) + oofs ; dst layout [e][*][R]
__global__ __launch_bounds__(256) void wcvtT_kernel(const float* __restrict__ src,
                                                    unsigned short* __restrict__ dst,
                                                    int R, int C, int ostep, int oofs,
                                                    size_t dexp)
{
  __shared__ unsigned short ls[64 * 72];     // [r][c], stride 72 (pad)
  const int tilesC = C >> 6;
  const int tpe = (R >> 6) * tilesC;
  const int b = blockIdx.x;
  const int e = b / tpe, rem = b - e * tpe;
  const int r0 = (rem / tilesC) * 64, c0 = (rem % tilesC) * 64;
  const float* sp = src + (size_t)e * R * C + (size_t)r0 * C + c0;
  const int t = threadIdx.x;
  const int rsub = t >> 4, cs = (t & 15) * 4;
#pragma unroll
  for (int q = 0; q < 4; ++q){
    int r = rsub * 4 + q;
    float4 v = *(const float4*)(sp + (size_t)r * C + cs);
    unsigned short* lp = &ls[r * 72 + cs];
    lp[0] = f2bf(v.x); lp[1] = f2bf(v.y); lp[2] = f2bf(v.z); lp[3] = f2bf(v.w);
  }
  __syncthreads();
  const int c = t >> 2, rs = (t & 3) * 16;
  unsigned vv[16];
#pragma unroll
  for (int j = 0; j < 16; ++j) vv[j] = ls[(rs + j) * 72 + c];
  uint4 o0 = make_uint4(vv[0]|(vv[1]<<16),  vv[2]|(vv[3]<<16),
                        vv[4]|(vv[5]<<16),  vv[6]|(vv[7]<<16));
  uint4 o1 = make_uint4(vv[8]|(vv[9]<<16),  vv[10]|(vv[11]<<16),
                        vv[12]|(vv[13]<<16), vv[14]|(vv[15]<<16));
  const int gc = c0 + c;
  const int np = (gc >> 4) * ostep + (gc & 15) + oofs;
  unsigned short* dq = dst + (size_t)e * dexp + (size_t)np * R + r0;
  *(uint4*)(dq + rs)     = o0;
  *(uint4*)(dq + rs + 8) = o1;
}

// ---------------- gate: logits (fp32 exact), softmax, top-2 -------------------
__global__ __launch_bounds__(256) void gate_kernel(
    const float* __restrict__ x, const float* __restrict__ wgate,
    float* __restrict__ logits_out, float* __restrict__ topk_p,
    int* __restrict__ flat_e, float* __restrict__ rl_out)
{
  __shared__ float xs[4][HDIM];
  const int w = threadIdx.x >> 6, lane = threadIdx.x & 63;
  const int tok = blockIdx.x * 4 + w;
  const float4* xr = (const float4*)(x + (size_t)tok * HDIM);
  float4* xd = (float4*)(&xs[w][0]);
#pragma unroll
  for (int j = 0; j < 4; ++j) xd[j * 64 + lane] = xr[j * 64 + lane];
  __syncthreads();
  float acc = 0.f;
#pragma unroll 8
  for (int h = 0; h < HDIM; ++h)
    acc = fmaf(xs[w][h], wgate[h * NEXP + lane], acc);
  logits_out[(size_t)tok * NEXP + lane] = acc;
  float m = acc;
#pragma unroll
  for (int d = 1; d < 64; d <<= 1) m = fmaxf(m, __shfl_xor(m, d));
  float p = expf(acc - m);
  float sum = p;
#pragma unroll
  for (int d = 1; d < 64; d <<= 1) sum += __shfl_xor(sum, d);
  float prob = p / sum;
  float v = prob; int idx = lane;
#pragma unroll
  for (int d = 1; d < 64; d <<= 1){
    float ov = __shfl_xor(v, d); int oi = __shfl_xor(idx, d);
    if (ov > v || (ov == v && oi < idx)){ v = ov; idx = oi; }
  }
  const int e1 = idx; const float p1 = v;
  v = (lane == e1) ? -1.f : prob; idx = lane;
#pragma unroll
  for (int d = 1; d < 64; d <<= 1){
    float ov = __shfl_xor(v, d); int oi = __shfl_xor(idx, d);
    if (ov > v || (ov == v && oi < idx)){ v = ov; idx = oi; }
  }
  if (lane == 0){
    flat_e[tok * 2]     = e1;  flat_e[tok * 2 + 1] = idx;
    topk_p[tok * 2]     = p1;  topk_p[tok * 2 + 1] = v;
  }
  if (tok == 0 && lane == 0) rl_out[0] = 0.f;
}

// ---------------- per-chunk expert histogram ---------------------------------
__global__ __launch_bounds__(256) void hist_kernel(const int* __restrict__ flat_e,
                                                   int* __restrict__ counts)
{
  __shared__ int hh[NEXP];
  const int t = threadIdx.x;
  if (t < NEXP) hh[t] = 0;
  __syncthreads();
  const int e = flat_e[blockIdx.x * 256 + t];
  atomicAdd(&hh[e], 1);
  __syncthreads();
  if (t < NEXP) counts[blockIdx.x * NEXP + t] = hh[t];
}

// ---------------- per-expert exclusive scan over chunks ----------------------
__global__ __launch_bounds__(256) void offsets_kernel(const int* __restrict__ counts,
                                                      int* __restrict__ offs,
                                                      int* __restrict__ etot)
{
  const int w = threadIdx.x >> 6, lane = threadIdx.x & 63;
  const int e = blockIdx.x * 4 + w;
  int v0 = counts[lane * NEXP + e];
  int v1 = counts[(64 + lane) * NEXP + e];
  int s0 = v0, s1 = v1;
#pragma unroll
  for (int d = 1; d < 64; d <<= 1){
    int n0 = __shfl_up(s0, d); if (lane >= d) s0 += n0;
    int n1 = __shfl_up(s1, d); if (lane >= d) s1 += n1;
  }
  const int tot0 = __shfl(s0, 63);
  offs[lane * NEXP + e]        = s0 - v0;
  offs[(64 + lane) * NEXP + e] = tot0 + s1 - v1;
  if (lane == 63) etot[e] = tot0 + s1;
}

// ---------------- ordered placement + slot map + cw --------------------------
__global__ __launch_bounds__(256) void place_kernel(
    const int* __restrict__ flat_e, const float* __restrict__ topk_p,
    const int* __restrict__ offs, int* __restrict__ entry_slot,
    int* __restrict__ token_of_slot, float* __restrict__ cw_out)
{
  __shared__ int es[256];
  __shared__ float wsh[256];
  const int t = threadIdx.x;
  const int i = blockIdx.x * 256 + t;
  const int e = flat_e[i];
  es[t] = e;
  __syncthreads();
  int local = 0;
  for (int j = 0; j < t; ++j) local += (es[j] == e);
  const int pos = offs[blockIdx.x * NEXP + e] + local;
  const bool valid = pos < CAPC;
  const int slot = e * CAPC + pos;
  entry_slot[i] = valid ? slot : -1;
  if (valid) token_of_slot[slot] = i >> 1;
  const float p = topk_p[i];
  wsh[t] = valid ? p : 0.f;
  __syncthreads();
  const float wme = wsh[t], wo = wsh[t ^ 1];
  cw_out[i] = wme / fmaxf(wme + wo, 1e-12f);
}

// ---------------- build dispatched A (bf16) ----------------------------------
__global__ __launch_bounds__(256) void adisp_kernel(
    const float* __restrict__ x, const int* __restrict__ token_of_slot,
    const int* __restrict__ etot, unsigned short* __restrict__ adisp)
{
  const int slot = blockIdx.x;
  const int e = slot / CAPC, c = slot - e * CAPC;
  int cnt = etot[e]; if (cnt > CAPC) cnt = CAPC;
  if (c >= cnt) return;
  const int tok = token_of_slot[slot];
  const int t = threadIdx.x;
  float4 v = ((const float4*)(x + (size_t)tok * HDIM))[t];
  ushort4 o; o.x = f2bf(v.x); o.y = f2bf(v.y); o.z = f2bf(v.z); o.w = f2bf(v.w);
  ((ushort4*)(adisp + (size_t)slot * HDIM))[t] = o;
}

// Tiles [rows][32 k] bf16, 64B rows = 4 x 16B units. Unit c: row=c>>2,
// jsrc=(c&3)^((row>>1)&3) (2-way bank alias = free). Staged gload_lds w16,
// linear LDS dest, pre-swizzled source. Fragment: ds_read_b128 at
// row*32 + ((lane>>4)^((row>>1)&3))*8. (Verified R4..R10.)

// vmcnt tail helper: t <= NK-4 -> 6 ; t == NK-3 -> 3 ; else 0
#define STEP_WAIT(T, NK)                                              \
  if ((T) <= (NK) - 4)      asm volatile("s_waitcnt vmcnt(6)" ::: "memory"); \
  else if ((T) == (NK) - 3) asm volatile("s_waitcnt vmcnt(3)" ::: "memory"); \
  else                      asm volatile("s_waitcnt vmcnt(0)" ::: "memory");

// ---------------- gemm1: fused g,u + SwiGLU (merged wgu), m201 schedule ------
__global__ __launch_bounds__(512) void gemm1_kernel(
    const unsigned short* __restrict__ adisp,
    const unsigned short* __restrict__ wgu,   // [e][1024 merged][HDIM]
    unsigned short* __restrict__ hbuf)
{
  constexpr int NK = HDIM / 32;                // 32 K-steps
  __shared__ unsigned short As[4][128 * 32];   // 8 KB each
  __shared__ unsigned short Bs[4][256 * 32];   // 16 KB each  -> total 96 KB
  const int bb = blockIdx.x;
  const int lb = (bb & 7) * 160 + (bb >> 3);   // 1280 blocks, 1280%8==0
  const int e = lb / 20; const int r2 = lb - e * 20;
  const int nt = r2 / 5, mt = r2 - nt * 5;     // mt innermost: 5 share B panel
  const int t = threadIdx.x, w = t >> 6, lane = t & 63;
  const int wr = w >> 2, wc = w & 3;           // 2M x 4N waves, wave 64x64
  const size_t arow0 = (size_t)e * CAPC + (size_t)mt * 128;
  const unsigned short* abase = adisp + arow0 * HDIM;
  const unsigned short* bbase = wgu + ((size_t)e * 1024 + (size_t)nt * 256) * HDIM;

  int aoff;        // A: 512 units, 1/thread
  { int row = t >> 2, jsrc = (t & 3) ^ ((row >> 1) & 3);
    aoff = row * HDIM + jsrc * 8; }
  int boff[2];     // B: 1024 units, 2/thread
#pragma unroll
  for (int rr = 0; rr < 2; ++rr){
    int c = rr * 512 + t, row = c >> 2, jsrc = (c & 3) ^ ((row >> 1) & 3);
    boff[rr] = row * HDIM + jsrc * 8;
  }

  f32x4 acc[4][4];
#pragma unroll
  for (int i = 0; i < 4; ++i)
#pragma unroll
    for (int j = 0; j < 4; ++j)
#pragma unroll
      for (int q = 0; q < 4; ++q) acc[i][j][q] = 0.f;

  auto stage = [&](int buf, int tk){
    const int kb = tk * 32;
    gload_lds16(abase + aoff + kb, &As[buf][w * 64 * 8]);
    gload_lds16(bbase + boff[0] + kb, &Bs[buf][w * 64 * 8]);
    gload_lds16(bbase + boff[1] + kb, &Bs[buf][(512 + w * 64) * 8]);
  };

  // prologue: tiles 0,1,2 in flight (9 loads/wave)
  stage(0, 0); stage(1, 1); stage(2, 2);
  asm volatile("s_waitcnt vmcnt(6)" ::: "memory");   // tile 0 landed (this wave)
  __builtin_amdgcn_s_barrier();                      // -> landed for all waves
  __builtin_amdgcn_sched_barrier(0);

  const int j8 = lane >> 4;
  for (int ti = 0; ti < NK; ++ti){
    const int cur = ti & 3;
    bf16x8 af[4], bfr[2];
    // ---- phase 0: A frags + B n0,n1 ; issue next staging ----
#pragma unroll
    for (int m = 0; m < 4; ++m){
      int row = wr * 64 + m * 16 + (lane & 15);
      af[m] = *(const bf16x8*)&As[cur][row * 32 + ((j8 ^ ((row >> 1) & 3)) * 8)];
    }
#pragma unroll
    for (int n = 0; n < 2; ++n){
      int brow = wc * 64 + n * 16 + (lane & 15);
      bfr[n] = *(const bf16x8*)&Bs[cur][brow * 32 + ((j8 ^ ((brow >> 1) & 3)) * 8)];
    }
    if (ti + 3 < NK) stage((ti + 3) & 3, ti + 3);
    __builtin_amdgcn_s_barrier();
    asm volatile("s_waitcnt lgkmcnt(0)" ::: "memory");
    __builtin_amdgcn_sched_barrier(0);
    __builtin_amdgcn_s_setprio(1);
#pragma unroll
    for (int m = 0; m < 4; ++m)
#pragma unroll
      for (int n = 0; n < 2; ++n)
        acc[m][n] = __builtin_amdgcn_mfma_f32_16x16x32_bf16(af[m], bfr[n], acc[m][n], 0, 0, 0);
    __builtin_amdgcn_s_setprio(0);
    __builtin_amdgcn_s_barrier();
    __builtin_amdgcn_sched_barrier(0);
    // ---- phase 1: B n2,n3 ----
#pragma unroll
    for (int n = 0; n < 2; ++n){
      int brow = wc * 64 + (2 + n) * 16 + (lane & 15);
      bfr[n] = *(const bf16x8*)&Bs[cur][brow * 32 + ((j8 ^ ((brow >> 1) & 3)) * 8)];
    }
    __builtin_amdgcn_s_barrier();
    asm volatile("s_waitcnt lgkmcnt(0)" ::: "memory");
    __builtin_amdgcn_sched_barrier(0);
    __builtin_amdgcn_s_setprio(1);
#pragma unroll
    for (int m = 0; m < 4; ++m)
#pragma unroll
      for (int n = 0; n < 2; ++n)
        acc[m][2 + n] = __builtin_amdgcn_mfma_f32_16x16x32_bf16(af[m], bfr[n], acc[m][2 + n], 0, 0, 0);
    __builtin_amdgcn_s_setprio(0);
    // step-ending wait: next tile's loads landed (per-wave) + barrier (block)
    STEP_WAIT(ti, NK);
    __builtin_amdgcn_s_barrier();
    __builtin_amdgcn_sched_barrier(0);
  }

  // epilogue: merged cols interleave g/u at 16: acc[m][2j]=g, acc[m][2j+1]=u
#pragma unroll
  for (int m = 0; m < 4; ++m)
#pragma unroll
    for (int j = 0; j < 2; ++j)
#pragma unroll
      for (int q = 0; q < 4; ++q){
        int row = wr * 64 + m * 16 + (lane >> 4) * 4 + q;
        int col = (nt * 8 + wc * 2 + j) * 16 + (lane & 15);   // real g/u column
        float gv = acc[m][2 * j][q], uv = acc[m][2 * j + 1][q];
        float hv = gv / (1.f + expf(-gv)) * uv;
        hbuf[(arow0 + row) * IDIM + col] = f2bf(hv);
      }
}

// ---------------- gemm2: eo = h * Wd (bf16 out), m201 schedule ---------------
__global__ __launch_bounds__(512) void gemm2_kernel(
    const unsigned short* __restrict__ hbuf,
    const unsigned short* __restrict__ wdt,   // [e][HDIM n][IDIM k]
    unsigned short* __restrict__ eo)
{
  constexpr int NK = IDIM / 32;                // 16 K-steps
  __shared__ unsigned short As[4][128 * 32];
  __shared__ unsigned short Bs[4][256 * 32];
  const int bb = blockIdx.x;
  const int lb = (bb & 7) * 160 + (bb >> 3);   // 1280 blocks
  const int e = lb / 20; const int r2 = lb - e * 20;
  const int nt = r2 / 5, mt = r2 - nt * 5;
  const int t = threadIdx.x, w = t >> 6, lane = t & 63;
  const int wr = w >> 2, wc = w & 3;
  const size_t arow0 = (size_t)e * CAPC + (size_t)mt * 128;
  const unsigned short* abase = hbuf + arow0 * IDIM;
  const unsigned short* bbase = wdt + ((size_t)e * HDIM + (size_t)nt * 256) * IDIM;

  int aoff;
  { int row = t >> 2, jsrc = (t & 3) ^ ((row >> 1) & 3);
    aoff = row * IDIM + jsrc * 8; }
  int boff[2];
#pragma unroll
  for (int rr = 0; rr < 2; ++rr){
    int c = rr * 512 + t, row = c >> 2, jsrc = (c & 3) ^ ((row >> 1) & 3);
    boff[rr] = row * IDIM + jsrc * 8;
  }

  f32x4 acc[4][4];
#pragma unroll
  for (int i = 0; i < 4; ++i)
#pragma unroll
    for (int j = 0; j < 4; ++j)
#pragma unroll
      for (int q = 0; q < 4; ++q) acc[i][j][q] = 0.f;

  auto stage = [&](int buf, int tk){
    const int kb = tk * 32;
    gload_lds16(abase + aoff + kb, &As[buf][w * 64 * 8]);
    gload_lds16(bbase + boff[0] + kb, &Bs[buf][w * 64 * 8]);
    gload_lds16(bbase + boff[1] + kb, &Bs[buf][(512 + w * 64) * 8]);
  };

  stage(0, 0); stage(1, 1); stage(2, 2);
  asm volatile("s_waitcnt vmcnt(6)" ::: "memory");
  __builtin_amdgcn_s_barrier();
  __builtin_amdgcn_sched_barrier(0);

  const int j8 = lane >> 4;
  for (int ti = 0; ti < NK; ++ti){
    const int cur = ti & 3;
    bf16x8 af[4], bfr[2];
#pragma unroll
    for (int m = 0; m < 4; ++m){
      int row = wr * 64 + m * 16 + (lane & 15);
      af[m] = *(const bf16x8*)&As[cur][row * 32 + ((j8 ^ ((row >> 1) & 3)) * 8)];
    }
#pragma unroll
    for (int n = 0; n < 2; ++n){
      int brow = wc * 64 + n * 16 + (lane & 15);
      bfr[n] = *(const bf16x8*)&Bs[cur][brow * 32 + ((j8 ^ ((brow >> 1) & 3)) * 8)];
    }
    if (ti + 3 < NK) stage((ti + 3) & 3, ti + 3);
    __builtin_amdgcn_s_barrier();
    asm volatile("s_waitcnt lgkmcnt(0)" ::: "memory");
    __builtin_amdgcn_sched_barrier(0);
    __builtin_amdgcn_s_setprio(1);
#pragma unroll
    for (int m = 0; m < 4; ++m)
#pragma unroll
      for (int n = 0; n < 2; ++n)
        acc[m][n] = __builtin_amdgcn_mfma_f32_16x16x32_bf16(af[m], bfr[n], acc[m][n], 0, 0, 0);
    __builtin_amdgcn_s_setprio(0);
    __builtin_amdgcn_s_barrier();
    __builtin_amdgcn_sched_barrier(0);
#pragma unroll
    for (int n = 0; n < 2; ++n){
      int brow = wc * 64 + (2 + n) * 16 + (lane & 15);
      bfr[n] = *(const bf16x8*)&Bs[cur][brow * 32 + ((j8 ^ ((brow >> 1) & 3)) * 8)];
    }
    __builtin_amdgcn_s_barrier();
    asm volatile("s_waitcnt lgkmcnt(0)" ::: "memory");
    __builtin_amdgcn_sched_barrier(0);
    __builtin_amdgcn_s_setprio(1);
#pragma unroll
    for (int m = 0; m < 4; ++m)
#pragma unroll
      for (int n = 0; n < 2; ++n)
        acc[m][2 + n] = __builtin_amdgcn_mfma_f32_16x16x32_bf16(af[m], bfr[n], acc[m][2 + n], 0, 0, 0);
    __builtin_amdgcn_s_setprio(0);
    STEP_WAIT(ti, NK);
    __builtin_amdgcn_s_barrier();
    __builtin_amdgcn_sched_barrier(0);
  }

#pragma unroll
  for (int m = 0; m < 4; ++m)
#pragma unroll
    for (int n = 0; n < 4; ++n)
#pragma unroll
      for (int q = 0; q < 4; ++q){
        int row = wr * 64 + m * 16 + (lane >> 4) * 4 + q;
        int col = nt * 256 + wc * 64 + n * 16 + (lane & 15);
        eo[(arow0 + row) * HDIM + col] = f2bf(acc[m][n][q]);
      }
}

// ---------------- combine: out[s] = sum_k cw[s,k] * eo[slot(s,k)] ------------
__global__ __launch_bounds__(256) void combine_kernel(
    const unsigned short* __restrict__ eo, const int* __restrict__ entry_slot,
    const float* __restrict__ cw, float* __restrict__ out)
{
  const int s = blockIdx.x, t = threadIdx.x;
  const int s0 = entry_slot[2 * s], s1 = entry_slot[2 * s + 1];
  const float w0 = cw[2 * s], w1 = cw[2 * s + 1];
  const int c = t * 4;
  float r0 = 0.f, r1 = 0.f, r2 = 0.f, r3 = 0.f;
  if (s0 >= 0){
    ushort4 vq = *(const ushort4*)&eo[(size_t)s0 * HDIM + c];
    r0 += w0 * bf2f(vq.x); r1 += w0 * bf2f(vq.y); r2 += w0 * bf2f(vq.z); r3 += w0 * bf2f(vq.w);
  }
  if (s1 >= 0){
    ushort4 vq = *(const ushort4*)&eo[(size_t)s1 * HDIM + c];
    r0 += w1 * bf2f(vq.x); r1 += w1 * bf2f(vq.y); r2 += w1 * bf2f(vq.z); r3 += w1 * bf2f(vq.w);
  }
  ((float4*)(out + (size_t)s * HDIM))[t] = make_float4(r0, r1, r2, r3);
}

extern "C" void kernel_launch(void* const* d_in, const int* in_sizes, int n_in,
                              void* d_out, int out_size, void* d_ws, size_t ws_size,
                              hipStream_t stream) {
  (void)in_sizes; (void)n_in; (void)out_size; (void)ws_size;
  const float* x     = (const float*)d_in[0];
  const float* wgate = (const float*)d_in[1];
  const float* wg    = (const float*)d_in[2];
  const float* wu    = (const float*)d_in[3];
  const float* wd    = (const float*)d_in[4];

  float* out        = (float*)d_out;                         // [S,H]
  float* cw_out     = out + (size_t)S_TOK * HDIM;            // [S,2]
  float* rl_out     = cw_out + (size_t)S_TOK * 2;            // [1]
  float* logits_out = rl_out + 1;                            // [S,64]

  char* w8 = (char*)d_ws;
  size_t off = 0;
  auto alloc = [&](size_t bytes){ size_t r = off; off += (bytes + 255) & ~(size_t)255; return r; };
  int*   flat_e_ws        = (int*)  (w8 + alloc((size_t)32768 * 4));
  float* topk_p_ws        = (float*)(w8 + alloc((size_t)32768 * 4));
  int*   counts_ws        = (int*)  (w8 + alloc((size_t)NCHUNK * NEXP * 4));
  int*   offs_ws          = (int*)  (w8 + alloc((size_t)NCHUNK * NEXP * 4));
  int*   etot_ws          = (int*)  (w8 + alloc((size_t)NEXP * 4));
  int*   entry_slot_ws    = (int*)  (w8 + alloc((size_t)32768 * 4));
  int*   token_of_slot_ws = (int*)  (w8 + alloc((size_t)NEXP * CAPC * 4));
  unsigned short* hbuf_ws = (unsigned short*)(w8 + alloc((size_t)NEXP * CAPC * IDIM * 2));
  unsigned short* adisp_ws= (unsigned short*)(w8 + alloc((size_t)NEXP * CAPC * HDIM * 2));
  unsigned short* wgu_ws  = (unsigned short*)(w8 + alloc((size_t)NEXP * 2 * IDIM * HDIM * 2));
  unsigned short* eo_ws   = adisp_ws;   // alias: adisp dead after gemm1
  unsigned short* wdt_ws  = wgu_ws;     // alias: wgu dead after gemm1

  const int W8N = NEXP * HDIM * IDIM / 8;

  gate_kernel   <<<S_TOK / 4, 256, 0, stream>>>(x, wgate, logits_out, topk_p_ws, flat_e_ws, rl_out);
  hist_kernel   <<<NCHUNK,    256, 0, stream>>>(flat_e_ws, counts_ws);
  offsets_kernel<<<16,        256, 0, stream>>>(counts_ws, offs_ws, etot_ws);
  place_kernel  <<<NCHUNK,    256, 0, stream>>>(flat_e_ws, topk_p_ws, offs_ws,
                                                entry_slot_ws, token_of_slot_ws, cw_out);
  adisp_kernel  <<<NEXP * CAPC, 256, 0, stream>>>(x, token_of_slot_ws, etot_ws, adisp_ws);
  // merged 16-col interleave: g -> (n>>4)*32+(n&15), u -> +16; wd identity
  wcvtT_kernel  <<<NEXP * 128, 256, 0, stream>>>(wg, wgu_ws, HDIM, IDIM, 32, 0,
                                                 (size_t)1024 * HDIM);
  wcvtT_kernel  <<<NEXP * 128, 256, 0, stream>>>(wu, wgu_ws, HDIM, IDIM, 32, 16,
                                                 (size_t)1024 * HDIM);
  gemm1_kernel  <<<NEXP * 20, 512, 0, stream>>>(adisp_ws, wgu_ws, hbuf_ws);
  wcvtT_kernel  <<<NEXP * 128, 256, 0, stream>>>(wd, wdt_ws, IDIM, HDIM, 16, 0,
                                                 (size_t)HDIM * IDIM);
  gemm2_kernel  <<<NEXP * 20, 512, 0, stream>>>(hbuf_ws, wdt_ws, eo_ws);
  combine_kernel<<<S_TOK,     256, 0, stream>>>(eo_ws, entry_slot_ws, cw_out, out);
}

// Round 12
// 538.161 us; speedup vs baseline: 1.0683x; 1.0683x over previous
//
// Ernie4.5 MoE MLP — MI355X gfx950
// R12: R10 base (fused fp32->bf16 conversion in both GEMMs, bank-even staging,
//      3-buf distance-2 counted-vmcnt pipeline) + two fixes:
//      (1) early-exit mt-tiles beyond etot[e] (~20% of GEMM work skipped),
//      (2) staging pack via v_cvt_pk_bf16_f32 (1 inst / 2 floats, was ~6 VALU/elem).
// ws peak ~121 MB. eo aliases adisp (dead after gemm1).
#include <hip/hip_runtime.h>
#include <hip/hip_bf16.h>

constexpr int S_TOK = 16384;
constexpr int HDIM  = 1024;
constexpr int IDIM  = 512;
constexpr int NEXP  = 64;
constexpr int CAPC  = 640;
constexpr int NCHUNK = 128;   // 32768 routing entries / 256

typedef __attribute__((ext_vector_type(8))) short bf16x8;
typedef __attribute__((ext_vector_type(4))) short short4v;
typedef __attribute__((ext_vector_type(4))) float f32x4;

__device__ __forceinline__ float bf2f(unsigned short u){
  return __uint_as_float(((unsigned)u) << 16);
}
__device__ __forceinline__ unsigned short f2bf(float f){   // RNE bf16 (inputs finite)
  unsigned u = __float_as_uint(f);
  return (unsigned short)((u + 0x7fffu + ((u >> 16) & 1u)) >> 16);
}
// HW packed convert: dst = {lo16: bf16(a), hi16: bf16(b)} (RNE, gfx950)
__device__ __forceinline__ unsigned pk2cvt(float a, float b){
  unsigned r;
  asm volatile("v_cvt_pk_bf16_f32 %0, %1, %2" : "=v"(r) : "v"(a), "v"(b));
  return r;
}
__device__ __forceinline__ void gload_lds16(const void* g, void* l){
  __builtin_amdgcn_global_load_lds((const __attribute__((address_space(1))) unsigned*)g,
                                   (__attribute__((address_space(3))) unsigned*)l, 16, 0, 0);
}
__device__ __forceinline__ unsigned ldsoff(const void* p){ return (unsigned)(size_t)p; }
// two hw-transpose reads: parity-0 block and parity-1 block (+512B)
__device__ __forceinline__ void trread2(unsigned addr, short4v& lo, short4v& hi){
  asm volatile("ds_read_b64_tr_b16 %0, %2\n\t"
               "ds_read_b64_tr_b16 %1, %2 offset:512"
               : "=&v"(lo), "=&v"(hi) : "v"(addr));
}

// ---------------- gate: logits (fp32 exact), softmax, top-2 -------------------
__global__ __launch_bounds__(256) void gate_kernel(
    const float* __restrict__ x, const float* __restrict__ wgate,
    float* __restrict__ logits_out, float* __restrict__ topk_p,
    int* __restrict__ flat_e, float* __restrict__ rl_out)
{
  __shared__ float xs[4][HDIM];
  const int w = threadIdx.x >> 6, lane = threadIdx.x & 63;
  const int tok = blockIdx.x * 4 + w;
  const float4* xr = (const float4*)(x + (size_t)tok * HDIM);
  float4* xd = (float4*)(&xs[w][0]);
#pragma unroll
  for (int j = 0; j < 4; ++j) xd[j * 64 + lane] = xr[j * 64 + lane];
  __syncthreads();
  float acc = 0.f;
#pragma unroll 8
  for (int h = 0; h < HDIM; ++h)
    acc = fmaf(xs[w][h], wgate[h * NEXP + lane], acc);
  logits_out[(size_t)tok * NEXP + lane] = acc;
  float m = acc;
#pragma unroll
  for (int d = 1; d < 64; d <<= 1) m = fmaxf(m, __shfl_xor(m, d));
  float p = expf(acc - m);
  float sum = p;
#pragma unroll
  for (int d = 1; d < 64; d <<= 1) sum += __shfl_xor(sum, d);
  float prob = p / sum;
  float v = prob; int idx = lane;
#pragma unroll
  for (int d = 1; d < 64; d <<= 1){
    float ov = __shfl_xor(v, d); int oi = __shfl_xor(idx, d);
    if (ov > v || (ov == v && oi < idx)){ v = ov; idx = oi; }
  }
  const int e1 = idx; const float p1 = v;
  v = (lane == e1) ? -1.f : prob; idx = lane;
#pragma unroll
  for (int d = 1; d < 64; d <<= 1){
    float ov = __shfl_xor(v, d); int oi = __shfl_xor(idx, d);
    if (ov > v || (ov == v && oi < idx)){ v = ov; idx = oi; }
  }
  if (lane == 0){
    flat_e[tok * 2]     = e1;  flat_e[tok * 2 + 1] = idx;
    topk_p[tok * 2]     = p1;  topk_p[tok * 2 + 1] = v;
  }
  if (tok == 0 && lane == 0) rl_out[0] = 0.f;
}

// ---------------- per-chunk expert histogram ---------------------------------
__global__ __launch_bounds__(256) void hist_kernel(const int* __restrict__ flat_e,
                                                   int* __restrict__ counts)
{
  __shared__ int hh[NEXP];
  const int t = threadIdx.x;
  if (t < NEXP) hh[t] = 0;
  __syncthreads();
  const int e = flat_e[blockIdx.x * 256 + t];
  atomicAdd(&hh[e], 1);
  __syncthreads();
  if (t < NEXP) counts[blockIdx.x * NEXP + t] = hh[t];
}

// ---------------- per-expert exclusive scan over chunks ----------------------
__global__ __launch_bounds__(256) void offsets_kernel(const int* __restrict__ counts,
                                                      int* __restrict__ offs,
                                                      int* __restrict__ etot)
{
  const int w = threadIdx.x >> 6, lane = threadIdx.x & 63;
  const int e = blockIdx.x * 4 + w;
  int v0 = counts[lane * NEXP + e];
  int v1 = counts[(64 + lane) * NEXP + e];
  int s0 = v0, s1 = v1;
#pragma unroll
  for (int d = 1; d < 64; d <<= 1){
    int n0 = __shfl_up(s0, d); if (lane >= d) s0 += n0;
    int n1 = __shfl_up(s1, d); if (lane >= d) s1 += n1;
  }
  const int tot0 = __shfl(s0, 63);
  offs[lane * NEXP + e]        = s0 - v0;
  offs[(64 + lane) * NEXP + e] = tot0 + s1 - v1;
  if (lane == 63) etot[e] = tot0 + s1;
}

// ---------------- ordered placement + slot map + cw --------------------------
__global__ __launch_bounds__(256) void place_kernel(
    const int* __restrict__ flat_e, const float* __restrict__ topk_p,
    const int* __restrict__ offs, int* __restrict__ entry_slot,
    int* __restrict__ token_of_slot, float* __restrict__ cw_out)
{
  __shared__ int es[256];
  __shared__ float wsh[256];
  const int t = threadIdx.x;
  const int i = blockIdx.x * 256 + t;
  const int e = flat_e[i];
  es[t] = e;
  __syncthreads();
  int local = 0;
  for (int j = 0; j < t; ++j) local += (es[j] == e);
  const int pos = offs[blockIdx.x * NEXP + e] + local;
  const bool valid = pos < CAPC;
  const int slot = e * CAPC + pos;
  entry_slot[i] = valid ? slot : -1;
  if (valid) token_of_slot[slot] = i >> 1;
  const float p = topk_p[i];
  wsh[t] = valid ? p : 0.f;
  __syncthreads();
  const float wme = wsh[t], wo = wsh[t ^ 1];
  cw_out[i] = wme / fmaxf(wme + wo, 1e-12f);
}

// ---------------- build dispatched A (bf16) ----------------------------------
__global__ __launch_bounds__(256) void adisp_kernel(
    const float* __restrict__ x, const int* __restrict__ token_of_slot,
    const int* __restrict__ etot, unsigned short* __restrict__ adisp)
{
  const int slot = blockIdx.x;
  const int e = slot / CAPC, c = slot - e * CAPC;
  int cnt = etot[e]; if (cnt > CAPC) cnt = CAPC;
  if (c >= cnt) return;
  const int tok = token_of_slot[slot];
  const int t = threadIdx.x;
  float4 v = ((const float4*)(x + (size_t)tok * HDIM))[t];
  ushort4 o; o.x = f2bf(v.x); o.y = f2bf(v.y); o.z = f2bf(v.z); o.w = f2bf(v.w);
  ((ushort4*)(adisp + (size_t)slot * HDIM))[t] = o;
}

// A tile [128 rows][32 k] bf16: gload_lds w16, linear dest, source octet
// pre-swizzled: unit c -> row=c>>2, jsrc=(c&3)^((row>>1)&3); fragment read
// ds_read_b128 at row*32 + ((lane>>4)^((row>>1)&3))*8. (Verified R4..R11.)
// B panel [32 k][128 n] bf16, subtiled for tr_b16 (verified R2/R4/R5/R9/R10):
//   k = 8g+4par+dk, n = 16ng+8h8; ushort off = ((ng*2+par)*4+g)*64+dk*16+h8*8.
//   R10 thread map: (g,par)=wave, dk=(lane>>1)&3, h8=lane&1, ng=lane>>3 ->
//   write bank slot = lane&7 (2-way, free). tr-read: addr=cg*1024+8*lane, +512.

// ---------------- gemm1: fused g,u + SwiGLU; fp32 B in-GEMM ------------------
__global__ __launch_bounds__(512, 2) void gemm1_kernel(
    const unsigned short* __restrict__ adisp,
    const float* __restrict__ wg, const float* __restrict__ wu,
    const int* __restrict__ etot,
    unsigned short* __restrict__ hbuf)
{
  constexpr int NK1 = HDIM / 32;               // 32 K-steps
  __shared__ unsigned short As[3][128 * 32];   // 8 KB each
  __shared__ unsigned short Bs[3][2 * 128 * 32]; // panelG + panelU, 16 KB each
  const int bb = blockIdx.x;
  const int lb = (bb & 7) * 160 + (bb >> 3);   // 1280 blocks, 1280%8==0
  const int e = lb / 20; const int r2 = lb - e * 20;
  const int nt = r2 / 5, mt = r2 - nt * 5;     // mt innermost: 5 share B panel
  { int cnt = etot[e]; if (cnt > CAPC) cnt = CAPC;
    if (mt * 128 >= cnt) return; }             // early-exit empty capacity tiles
  const int t = threadIdx.x, w = t >> 6, lane = t & 63;
  const int wr = w >> 2, wc = w & 3;           // 2m x 4n waves
  const size_t arow0 = (size_t)e * CAPC + (size_t)mt * 128;
  const unsigned short* abase = adisp + arow0 * HDIM;
  const float* gsrc = wg + (size_t)e * HDIM * IDIM + nt * 128;
  const float* usrc = wu + (size_t)e * HDIM * IDIM + nt * 128;

  int aoff; { int row = t >> 2, jsrc = (t & 3) ^ ((row >> 1) & 3);
              aoff = row * HDIM + jsrc * 8; }
  // R10 bank-even staging map
  const int g_ = w >> 1, par = w & 1;
  const int dk = (lane >> 1) & 3, h8 = lane & 1, ng = lane >> 3;
  const int bk = 8 * g_ + 4 * par + dk;
  const int bn0 = ng * 16 + h8 * 8;
  const int bgo = bk * IDIM + bn0;             // fp32 source offset (+kb*IDIM)
  const unsigned bwo = (unsigned)((((ng * 2 + par) * 4 + g_) * 64) + dk * 16 + h8 * 8);

  f32x4 ag[4][2], au[4][2];
#pragma unroll
  for (int i = 0; i < 4; ++i)
#pragma unroll
    for (int j = 0; j < 2; ++j)
#pragma unroll
      for (int q = 0; q < 4; ++q){ ag[i][j][q] = 0.f; au[i][j][q] = 0.f; }

  float4 g0a, g0b, u0a, u0b, g1a, g1b, u1a, u1b;

#define G1_LOAD(KB, RA, RB, RC, RD) {                                          \
    const float* gp_ = gsrc + (size_t)(KB) * IDIM + bgo;                       \
    const float* up_ = usrc + (size_t)(KB) * IDIM + bgo;                       \
    RA = *(const float4*)gp_;       RB = *(const float4*)(gp_ + 4);            \
    RC = *(const float4*)up_;       RD = *(const float4*)(up_ + 4); }

#define G1_STORE(NB, WA, WB, WC, WD) {                                         \
    *(uint4*)&Bs[NB][bwo] = make_uint4(pk2cvt(WA.x,WA.y), pk2cvt(WA.z,WA.w),   \
                                       pk2cvt(WB.x,WB.y), pk2cvt(WB.z,WB.w));  \
    *(uint4*)&Bs[NB][4096 + bwo] = make_uint4(pk2cvt(WC.x,WC.y), pk2cvt(WC.z,WC.w), \
                                       pk2cvt(WD.x,WD.y), pk2cvt(WD.z,WD.w)); }

#define G1_STEP(TI, LA, LB, LC, LD, WA, WB, WC, WD) {                          \
    const int cur_ = (TI) % 3;                                                 \
    const bool pf_ = (TI) + 2 < NK1;                                           \
    if (pf_){                                                                  \
      const int kb2_ = ((TI) + 2) * 32;                                        \
      gload_lds16(abase + aoff + kb2_, &As[((TI) + 2) % 3][w * 64 * 8]);       \
      G1_LOAD(kb2_, LA, LB, LC, LD);                                           \
    }                                                                          \
    { const int j8_ = lane >> 4;                                               \
      bf16x8 af_[4], bg_[2], bu_[2];                                           \
      _Pragma("unroll")                                                        \
      for (int m = 0; m < 4; ++m){                                             \
        int row_ = wr * 64 + m * 16 + (lane & 15);                             \
        af_[m] = *(const bf16x8*)&As[cur_][row_ * 32 + ((j8_ ^ ((row_ >> 1) & 3)) * 8)]; \
      }                                                                        \
      const unsigned b0_ = ldsoff(&Bs[cur_][0]);                               \
      _Pragma("unroll")                                                        \
      for (int n = 0; n < 2; ++n){                                             \
        unsigned ao_ = (unsigned)((wc * 2 + n) * 1024 + lane * 8);             \
        short4v l0_, l1_, m0_, m1_;                                            \
        trread2(b0_ + ao_, l0_, l1_);                                          \
        bg_[n] = __builtin_shufflevector(l0_, l1_, 0,1,2,3,4,5,6,7);           \
        trread2(b0_ + 8192 + ao_, m0_, m1_);                                   \
        bu_[n] = __builtin_shufflevector(m0_, m1_, 0,1,2,3,4,5,6,7);           \
      }                                                                        \
      asm volatile("s_waitcnt lgkmcnt(0)" ::: "memory");                       \
      __builtin_amdgcn_sched_barrier(0);                                       \
      __builtin_amdgcn_s_setprio(1);                                           \
      _Pragma("unroll")                                                        \
      for (int m = 0; m < 4; ++m)                                              \
        _Pragma("unroll")                                                      \
        for (int n = 0; n < 2; ++n){                                           \
          ag[m][n] = __builtin_amdgcn_mfma_f32_16x16x32_bf16(af_[m], bg_[n], ag[m][n], 0, 0, 0); \
          au[m][n] = __builtin_amdgcn_mfma_f32_16x16x32_bf16(af_[m], bu_[n], au[m][n], 0, 0, 0); \
        }                                                                      \
      __builtin_amdgcn_s_setprio(0);                                           \
    }                                                                          \
    if ((TI) + 1 < NK1){                                                       \
      if (pf_) asm volatile("s_waitcnt vmcnt(5)" ::: "memory");                \
      else     asm volatile("s_waitcnt vmcnt(0)" ::: "memory");                \
      G1_STORE(((TI) + 1) % 3, WA, WB, WC, WD);                                \
    }                                                                          \
    asm volatile("s_waitcnt lgkmcnt(0)" ::: "memory");                         \
    __builtin_amdgcn_s_barrier();                                              \
    __builtin_amdgcn_sched_barrier(0);                                         \
  }

  // prologue: tiles 0,1 in flight (A via gload_lds, B via regs)
  gload_lds16(abase + aoff + 0,  &As[0][w * 64 * 8]);
  G1_LOAD(0,  g0a, g0b, u0a, u0b);
  gload_lds16(abase + aoff + 32, &As[1][w * 64 * 8]);
  G1_LOAD(32, g1a, g1b, u1a, u1b);
  asm volatile("s_waitcnt vmcnt(5)" ::: "memory");   // tile 0 landed
  G1_STORE(0, g0a, g0b, u0a, u0b);
  asm volatile("s_waitcnt lgkmcnt(0)" ::: "memory");
  __builtin_amdgcn_s_barrier();

  for (int tb = 0; tb < NK1; tb += 2){
    G1_STEP(tb,     g0a, g0b, u0a, u0b,  g1a, g1b, u1a, u1b);
    G1_STEP(tb + 1, g1a, g1b, u1a, u1b,  g0a, g0b, u0a, u0b);
  }
#undef G1_STEP
#undef G1_STORE
#undef G1_LOAD

  // epilogue: h = silu(g)*u -> bf16
#pragma unroll
  for (int m = 0; m < 4; ++m)
#pragma unroll
    for (int n = 0; n < 2; ++n)
#pragma unroll
      for (int q = 0; q < 4; ++q){
        int row = wr * 64 + m * 16 + (lane >> 4) * 4 + q;
        int col = nt * 128 + wc * 32 + n * 16 + (lane & 15);
        float gv = ag[m][n][q], uv = au[m][n][q];
        float hv = gv / (1.f + expf(-gv)) * uv;
        hbuf[(arow0 + row) * IDIM + col] = f2bf(hv);
      }
}

// ---------------- gemm2: eo = h * Wd; fp32 B in-GEMM -------------------------
__global__ __launch_bounds__(512, 2) void gemm2_kernel(
    const unsigned short* __restrict__ hbuf,
    const float* __restrict__ wd,
    const int* __restrict__ etot,
    unsigned short* __restrict__ eo)
{
  constexpr int NK2 = IDIM / 32;               // 16 K-steps
  __shared__ unsigned short As[3][128 * 32];
  __shared__ unsigned short Bs[3][2 * 128 * 32];  // two 128-n panels
  const int bb = blockIdx.x;
  const int lb = (bb & 7) * 160 + (bb >> 3);   // 1280 blocks
  const int e = lb / 20; const int r2 = lb - e * 20;
  const int nt = r2 / 5, mt = r2 - nt * 5;
  { int cnt = etot[e]; if (cnt > CAPC) cnt = CAPC;
    if (mt * 128 >= cnt) return; }             // early-exit empty capacity tiles
  const int t = threadIdx.x, w = t >> 6, lane = t & 63;
  const int wr = w >> 2, wc = w & 3;
  const size_t arow0 = (size_t)e * CAPC + (size_t)mt * 128;
  const unsigned short* abase = hbuf + arow0 * IDIM;
  const float* dsrc = wd + (size_t)e * IDIM * HDIM + nt * 256;

  int aoff; { int row = t >> 2, jsrc = (t & 3) ^ ((row >> 1) & 3);
              aoff = row * IDIM + jsrc * 8; }
  // R10 bank-even staging map
  const int g_ = w >> 1, par = w & 1;
  const int dk = (lane >> 1) & 3, h8 = lane & 1, ng = lane >> 3;
  const int bk = 8 * g_ + 4 * par + dk;
  const int bn0 = ng * 16 + h8 * 8;
  const int bgo = bk * HDIM + bn0;
  const unsigned bwo = (unsigned)((((ng * 2 + par) * 4 + g_) * 64) + dk * 16 + h8 * 8);

  f32x4 ac[4][4];
#pragma unroll
  for (int i = 0; i < 4; ++i)
#pragma unroll
    for (int j = 0; j < 4; ++j)
#pragma unroll
      for (int q = 0; q < 4; ++q) ac[i][j][q] = 0.f;

  float4 p0a, p0b, p1a, p1b, q0a, q0b, q1a, q1b;

#define G2_LOAD(KB, RA, RB, RC, RD) {                                          \
    const float* gp_ = dsrc + (size_t)(KB) * HDIM + bgo;                       \
    RA = *(const float4*)gp_;         RB = *(const float4*)(gp_ + 4);          \
    RC = *(const float4*)(gp_ + 128); RD = *(const float4*)(gp_ + 132); }

#define G2_STORE(NB, WA, WB, WC, WD) {                                         \
    *(uint4*)&Bs[NB][bwo] = make_uint4(pk2cvt(WA.x,WA.y), pk2cvt(WA.z,WA.w),   \
                                       pk2cvt(WB.x,WB.y), pk2cvt(WB.z,WB.w));  \
    *(uint4*)&Bs[NB][4096 + bwo] = make_uint4(pk2cvt(WC.x,WC.y), pk2cvt(WC.z,WC.w), \
                                       pk2cvt(WD.x,WD.y), pk2cvt(WD.z,WD.w)); }

#define G2_STEP(TI, LA, LB, LC, LD, WA, WB, WC, WD) {                          \
    const int cur_ = (TI) % 3;                                                 \
    const bool pf_ = (TI) + 2 < NK2;                                           \
    if (pf_){                                                                  \
      const int kb2_ = ((TI) + 2) * 32;                                        \
      gload_lds16(abase + aoff + kb2_, &As[((TI) + 2) % 3][w * 64 * 8]);       \
      G2_LOAD(kb2_, LA, LB, LC, LD);                                           \
    }                                                                          \
    { const int j8_ = lane >> 4;                                               \
      bf16x8 af_[4], bf_[4];                                                   \
      _Pragma("unroll")                                                        \
      for (int m = 0; m < 4; ++m){                                             \
        int row_ = wr * 64 + m * 16 + (lane & 15);                             \
        af_[m] = *(const bf16x8*)&As[cur_][row_ * 32 + ((j8_ ^ ((row_ >> 1) & 3)) * 8)]; \
      }                                                                        \
      const unsigned b0_ = ldsoff(&Bs[cur_][0]) + (unsigned)(wc >> 1) * 8192;  \
      _Pragma("unroll")                                                        \
      for (int n = 0; n < 4; ++n){                                             \
        unsigned ao_ = (unsigned)(((wc & 1) * 4 + n) * 1024 + lane * 8);       \
        short4v l0_, l1_;                                                      \
        trread2(b0_ + ao_, l0_, l1_);                                          \
        bf_[n] = __builtin_shufflevector(l0_, l1_, 0,1,2,3,4,5,6,7);           \
      }                                                                        \
      asm volatile("s_waitcnt lgkmcnt(0)" ::: "memory");                       \
      __builtin_amdgcn_sched_barrier(0);                                       \
      __builtin_amdgcn_s_setprio(1);                                           \
      _Pragma("unroll")                                                        \
      for (int m = 0; m < 4; ++m)                                              \
        _Pragma("unroll")                                                      \
        for (int n = 0; n < 4; ++n)                                            \
          ac[m][n] = __builtin_amdgcn_mfma_f32_16x16x32_bf16(af_[m], bf_[n], ac[m][n], 0, 0, 0); \
      __builtin_amdgcn_s_setprio(0);                                           \
    }                                                                          \
    if ((TI) + 1 < NK2){                                                       \
      if (pf_) asm volatile("s_waitcnt vmcnt(5)" ::: "memory");                \
      else     asm volatile("s_waitcnt vmcnt(0)" ::: "memory");                \
      G2_STORE(((TI) + 1) % 3, WA, WB, WC, WD);                                \
    }                                                                          \
    asm volatile("s_waitcnt lgkmcnt(0)" ::: "memory");                         \
    __builtin_amdgcn_s_barrier();                                              \
    __builtin_amdgcn_sched_barrier(0);                                         \
  }

  gload_lds16(abase + aoff + 0,  &As[0][w * 64 * 8]);
  G2_LOAD(0,  p0a, p0b, q0a, q0b);
  gload_lds16(abase + aoff + 32, &As[1][w * 64 * 8]);
  G2_LOAD(32, p1a, p1b, q1a, q1b);
  asm volatile("s_waitcnt vmcnt(5)" ::: "memory");
  G2_STORE(0, p0a, p0b, q0a, q0b);
  asm volatile("s_waitcnt lgkmcnt(0)" ::: "memory");
  __builtin_amdgcn_s_barrier();

  for (int tb = 0; tb < NK2; tb += 2){
    G2_STEP(tb,     p0a, p0b, q0a, q0b,  p1a, p1b, q1a, q1b);
    G2_STEP(tb + 1, p1a, p1b, q1a, q1b,  p0a, p0b, q0a, q0b);
  }
#undef G2_STEP
#undef G2_STORE
#undef G2_LOAD

#pragma unroll
  for (int m = 0; m < 4; ++m)
#pragma unroll
    for (int n = 0; n < 4; ++n)
#pragma unroll
      for (int q = 0; q < 4; ++q){
        int row = wr * 64 + m * 16 + (lane >> 4) * 4 + q;
        int col = nt * 256 + wc * 64 + n * 16 + (lane & 15);
        eo[(arow0 + row) * HDIM + col] = f2bf(ac[m][n][q]);
      }
}

// ---------------- combine: out[s] = sum_k cw[s,k] * eo[slot(s,k)] ------------
__global__ __launch_bounds__(256) void combine_kernel(
    const unsigned short* __restrict__ eo, const int* __restrict__ entry_slot,
    const float* __restrict__ cw, float* __restrict__ out)
{
  const int s = blockIdx.x, t = threadIdx.x;
  const int s0 = entry_slot[2 * s], s1 = entry_slot[2 * s + 1];
  const float w0 = cw[2 * s], w1 = cw[2 * s + 1];
  const int c = t * 4;
  float r0 = 0.f, r1 = 0.f, r2 = 0.f, r3 = 0.f;
  if (s0 >= 0){
    ushort4 vq = *(const ushort4*)&eo[(size_t)s0 * HDIM + c];
    r0 += w0 * bf2f(vq.x); r1 += w0 * bf2f(vq.y); r2 += w0 * bf2f(vq.z); r3 += w0 * bf2f(vq.w);
  }
  if (s1 >= 0){
    ushort4 vq = *(const ushort4*)&eo[(size_t)s1 * HDIM + c];
    r0 += w1 * bf2f(vq.x); r1 += w1 * bf2f(vq.y); r2 += w1 * bf2f(vq.z); r3 += w1 * bf2f(vq.w);
  }
  ((float4*)(out + (size_t)s * HDIM))[t] = make_float4(r0, r1, r2, r3);
}

extern "C" void kernel_launch(void* const* d_in, const int* in_sizes, int n_in,
                              void* d_out, int out_size, void* d_ws, size_t ws_size,
                              hipStream_t stream) {
  (void)in_sizes; (void)n_in; (void)out_size; (void)ws_size;
  const float* x     = (const float*)d_in[0];
  const float* wgate = (const float*)d_in[1];
  const float* wg    = (const float*)d_in[2];
  const float* wu    = (const float*)d_in[3];
  const float* wd    = (const float*)d_in[4];

  float* out        = (float*)d_out;                         // [S,H]
  float* cw_out     = out + (size_t)S_TOK * HDIM;            // [S,2]
  float* rl_out     = cw_out + (size_t)S_TOK * 2;            // [1]
  float* logits_out = rl_out + 1;                            // [S,64]

  char* w8 = (char*)d_ws;
  size_t off = 0;
  auto alloc = [&](size_t bytes){ size_t r = off; off += (bytes + 255) & ~(size_t)255; return r; };
  int*   flat_e_ws        = (int*)  (w8 + alloc((size_t)32768 * 4));
  float* topk_p_ws        = (float*)(w8 + alloc((size_t)32768 * 4));
  int*   counts_ws        = (int*)  (w8 + alloc((size_t)NCHUNK * NEXP * 4));
  int*   offs_ws          = (int*)  (w8 + alloc((size_t)NCHUNK * NEXP * 4));
  int*   etot_ws          = (int*)  (w8 + alloc((size_t)NEXP * 4));
  int*   entry_slot_ws    = (int*)  (w8 + alloc((size_t)32768 * 4));
  int*   token_of_slot_ws = (int*)  (w8 + alloc((size_t)NEXP * CAPC * 4));
  unsigned short* hbuf_ws = (unsigned short*)(w8 + alloc((size_t)NEXP * CAPC * IDIM * 2));
  unsigned short* adisp_ws= (unsigned short*)(w8 + alloc((size_t)NEXP * CAPC * HDIM * 2));
  unsigned short* eo_ws   = adisp_ws;   // alias: adisp dead after gemm1

  gate_kernel   <<<S_TOK / 4, 256, 0, stream>>>(x, wgate, logits_out, topk_p_ws, flat_e_ws, rl_out);
  hist_kernel   <<<NCHUNK,    256, 0, stream>>>(flat_e_ws, counts_ws);
  offsets_kernel<<<16,        256, 0, stream>>>(counts_ws, offs_ws, etot_ws);
  place_kernel  <<<NCHUNK,    256, 0, stream>>>(flat_e_ws, topk_p_ws, offs_ws,
                                                entry_slot_ws, token_of_slot_ws, cw_out);
  adisp_kernel  <<<NEXP * CAPC, 256, 0, stream>>>(x, token_of_slot_ws, etot_ws, adisp_ws);
  gemm1_kernel  <<<NEXP * 20, 512, 0, stream>>>(adisp_ws, wg, wu, etot_ws, hbuf_ws);
  gemm2_kernel  <<<NEXP * 20, 512, 0, stream>>>(hbuf_ws, wd, etot_ws, eo_ws);
  combine_kernel<<<S_TOK,     256, 0, stream>>>(eo_ws, entry_slot_ws, cw_out, out);
}

// Round 13
// 514.445 us; speedup vs baseline: 1.1175x; 1.0461x over previous
//
// Ernie4.5 MoE MLP — MI355X gfx950
// R13: switch both GEMMs to mfma_f32_32x32x16_bf16 (2x FLOP per operand byte
//      and per issue slot vs 16x16x32 -> halves the LDS-read bound that pins
//      MfmaUtil at 12%). R12's verified skeleton kept: fused fp32->bf16 staging
//      (cvt_pk, bank-even map), tr_b16 subtiled B (re-derived block indices for
//      32-wide fragments), A swizzle unchanged, 3-buf distance-2 counted-vmcnt,
//      early-exit empty capacity tiles.
// ws peak ~121 MB. eo aliases adisp (dead after gemm1).
#include <hip/hip_runtime.h>
#include <hip/hip_bf16.h>

constexpr int S_TOK = 16384;
constexpr int HDIM  = 1024;
constexpr int IDIM  = 512;
constexpr int NEXP  = 64;
constexpr int CAPC  = 640;
constexpr int NCHUNK = 128;   // 32768 routing entries / 256

typedef __attribute__((ext_vector_type(8))) short bf16x8;
typedef __attribute__((ext_vector_type(4))) short short4v;
typedef __attribute__((ext_vector_type(16))) float f32x16;

__device__ __forceinline__ float bf2f(unsigned short u){
  return __uint_as_float(((unsigned)u) << 16);
}
__device__ __forceinline__ unsigned short f2bf(float f){   // RNE bf16 (inputs finite)
  unsigned u = __float_as_uint(f);
  return (unsigned short)((u + 0x7fffu + ((u >> 16) & 1u)) >> 16);
}
// HW packed convert: dst = {lo16: bf16(a), hi16: bf16(b)} (RNE, gfx950)
__device__ __forceinline__ unsigned pk2cvt(float a, float b){
  unsigned r;
  asm volatile("v_cvt_pk_bf16_f32 %0, %1, %2" : "=v"(r) : "v"(a), "v"(b));
  return r;
}
__device__ __forceinline__ void gload_lds16(const void* g, void* l){
  __builtin_amdgcn_global_load_lds((const __attribute__((address_space(1))) unsigned*)g,
                                   (__attribute__((address_space(3))) unsigned*)l, 16, 0, 0);
}
__device__ __forceinline__ unsigned ldsoff(const void* p){ return (unsigned)(size_t)p; }
// two hw-transpose reads: j 0..3 (+0) and j 4..7 (+128B)
__device__ __forceinline__ void trread2(unsigned addr, short4v& lo, short4v& hi){
  asm volatile("ds_read_b64_tr_b16 %0, %2\n\t"
               "ds_read_b64_tr_b16 %1, %2 offset:128"
               : "=&v"(lo), "=&v"(hi) : "v"(addr));
}

// ---------------- gate: logits (fp32 exact), softmax, top-2 -------------------
__global__ __launch_bounds__(256) void gate_kernel(
    const float* __restrict__ x, const float* __restrict__ wgate,
    float* __restrict__ logits_out, float* __restrict__ topk_p,
    int* __restrict__ flat_e, float* __restrict__ rl_out)
{
  __shared__ float xs[4][HDIM];
  const int w = threadIdx.x >> 6, lane = threadIdx.x & 63;
  const int tok = blockIdx.x * 4 + w;
  const float4* xr = (const float4*)(x + (size_t)tok * HDIM);
  float4* xd = (float4*)(&xs[w][0]);
#pragma unroll
  for (int j = 0; j < 4; ++j) xd[j * 64 + lane] = xr[j * 64 + lane];
  __syncthreads();
  float acc = 0.f;
#pragma unroll 8
  for (int h = 0; h < HDIM; ++h)
    acc = fmaf(xs[w][h], wgate[h * NEXP + lane], acc);
  logits_out[(size_t)tok * NEXP + lane] = acc;
  float m = acc;
#pragma unroll
  for (int d = 1; d < 64; d <<= 1) m = fmaxf(m, __shfl_xor(m, d));
  float p = expf(acc - m);
  float sum = p;
#pragma unroll
  for (int d = 1; d < 64; d <<= 1) sum += __shfl_xor(sum, d);
  float prob = p / sum;
  float v = prob; int idx = lane;
#pragma unroll
  for (int d = 1; d < 64; d <<= 1){
    float ov = __shfl_xor(v, d); int oi = __shfl_xor(idx, d);
    if (ov > v || (ov == v && oi < idx)){ v = ov; idx = oi; }
  }
  const int e1 = idx; const float p1 = v;
  v = (lane == e1) ? -1.f : prob; idx = lane;
#pragma unroll
  for (int d = 1; d < 64; d <<= 1){
    float ov = __shfl_xor(v, d); int oi = __shfl_xor(idx, d);
    if (ov > v || (ov == v && oi < idx)){ v = ov; idx = oi; }
  }
  if (lane == 0){
    flat_e[tok * 2]     = e1;  flat_e[tok * 2 + 1] = idx;
    topk_p[tok * 2]     = p1;  topk_p[tok * 2 + 1] = v;
  }
  if (tok == 0 && lane == 0) rl_out[0] = 0.f;
}

// ---------------- per-chunk expert histogram ---------------------------------
__global__ __launch_bounds__(256) void hist_kernel(const int* __restrict__ flat_e,
                                                   int* __restrict__ counts)
{
  __shared__ int hh[NEXP];
  const int t = threadIdx.x;
  if (t < NEXP) hh[t] = 0;
  __syncthreads();
  const int e = flat_e[blockIdx.x * 256 + t];
  atomicAdd(&hh[e], 1);
  __syncthreads();
  if (t < NEXP) counts[blockIdx.x * NEXP + t] = hh[t];
}

// ---------------- per-expert exclusive scan over chunks ----------------------
__global__ __launch_bounds__(256) void offsets_kernel(const int* __restrict__ counts,
                                                      int* __restrict__ offs,
                                                      int* __restrict__ etot)
{
  const int w = threadIdx.x >> 6, lane = threadIdx.x & 63;
  const int e = blockIdx.x * 4 + w;
  int v0 = counts[lane * NEXP + e];
  int v1 = counts[(64 + lane) * NEXP + e];
  int s0 = v0, s1 = v1;
#pragma unroll
  for (int d = 1; d < 64; d <<= 1){
    int n0 = __shfl_up(s0, d); if (lane >= d) s0 += n0;
    int n1 = __shfl_up(s1, d); if (lane >= d) s1 += n1;
  }
  const int tot0 = __shfl(s0, 63);
  offs[lane * NEXP + e]        = s0 - v0;
  offs[(64 + lane) * NEXP + e] = tot0 + s1 - v1;
  if (lane == 63) etot[e] = tot0 + s1;
}

// ---------------- ordered placement + slot map + cw --------------------------
__global__ __launch_bounds__(256) void place_kernel(
    const int* __restrict__ flat_e, const float* __restrict__ topk_p,
    const int* __restrict__ offs, int* __restrict__ entry_slot,
    int* __restrict__ token_of_slot, float* __restrict__ cw_out)
{
  __shared__ int es[256];
  __shared__ float wsh[256];
  const int t = threadIdx.x;
  const int i = blockIdx.x * 256 + t;
  const int e = flat_e[i];
  es[t] = e;
  __syncthreads();
  int local = 0;
  for (int j = 0; j < t; ++j) local += (es[j] == e);
  const int pos = offs[blockIdx.x * NEXP + e] + local;
  const bool valid = pos < CAPC;
  const int slot = e * CAPC + pos;
  entry_slot[i] = valid ? slot : -1;
  if (valid) token_of_slot[slot] = i >> 1;
  const float p = topk_p[i];
  wsh[t] = valid ? p : 0.f;
  __syncthreads();
  const float wme = wsh[t], wo = wsh[t ^ 1];
  cw_out[i] = wme / fmaxf(wme + wo, 1e-12f);
}

// ---------------- build dispatched A (bf16) ----------------------------------
__global__ __launch_bounds__(256) void adisp_kernel(
    const float* __restrict__ x, const int* __restrict__ token_of_slot,
    const int* __restrict__ etot, unsigned short* __restrict__ adisp)
{
  const int slot = blockIdx.x;
  const int e = slot / CAPC, c = slot - e * CAPC;
  int cnt = etot[e]; if (cnt > CAPC) cnt = CAPC;
  if (c >= cnt) return;
  const int tok = token_of_slot[slot];
  const int t = threadIdx.x;
  float4 v = ((const float4*)(x + (size_t)tok * HDIM))[t];
  ushort4 o; o.x = f2bf(v.x); o.y = f2bf(v.y); o.z = f2bf(v.z); o.w = f2bf(v.w);
  ((ushort4*)(adisp + (size_t)slot * HDIM))[t] = o;
}

// A tile [128 rows][32 k] bf16 (unchanged, verified R4..R12). 32x32 fragment:
//   row = wbase + (lane&31), koct = ks*2 + (lane>>5), b128 at
//   row*32 + ((koct ^ ((row>>1)&3))*8)  -> lane gets k = 16ks+8(l>>5)+j.
// B panel [32k][W n] bf16, subtiled [4k][16n] for tr_b16, 32x32 fragments:
//   ushort off(k,n) = n32*1024 + ks*512 + (khalf*2+n16)*128 + par*64 + dk*16 + h8*8
//   where k = 16ks+8khalf+4par+dk, n = 32n32+16n16+8h8+...
//   tr read (wave n-group G, step ks): byte addr = base + G*2048 + ks*1024 +
//   (lane>>4)*256 + (lane&15)*8, pair offsets +0/+128 -> lane l gets
//   B[16ks+8(l>>5)+j][32G+(l&31)]  (same group-transpose contract as R2..R12).
// Staging thread map (bank-even): h8=lane&1, dk=(lane>>1)&3, n16=(lane>>3)&1,
//   n32=lane>>4 ; (ks,khalf,par) = (w>>2,(w>>1)&1,w&1).

// ---------------- gemm1: fused g,u + SwiGLU; 32x32 MFMA ----------------------
__global__ __launch_bounds__(512, 2) void gemm1_kernel(
    const unsigned short* __restrict__ adisp,
    const float* __restrict__ wg, const float* __restrict__ wu,
    const int* __restrict__ etot,
    unsigned short* __restrict__ hbuf)
{
  constexpr int NK1 = HDIM / 32;               // 32 K-steps
  __shared__ unsigned short As[3][128 * 32];   // 8 KB each
  __shared__ unsigned short Bs[3][2 * 128 * 32]; // panelG + panelU, 16 KB each
  const int bb = blockIdx.x;
  const int lb = (bb & 7) * 160 + (bb >> 3);   // 1280 blocks, 1280%8==0
  const int e = lb / 20; const int r2 = lb - e * 20;
  const int nt = r2 / 5, mt = r2 - nt * 5;     // mt innermost: 5 share B panel
  { int cnt = etot[e]; if (cnt > CAPC) cnt = CAPC;
    if (mt * 128 >= cnt) return; }             // early-exit empty capacity tiles
  const int t = threadIdx.x, w = t >> 6, lane = t & 63;
  const int wr = w >> 2, wc = w & 3;           // 2m x 4n waves (wave 64m x 32h)
  const size_t arow0 = (size_t)e * CAPC + (size_t)mt * 128;
  const unsigned short* abase = adisp + arow0 * HDIM;
  const float* gsrc = wg + (size_t)e * HDIM * IDIM + nt * 128;
  const float* usrc = wu + (size_t)e * HDIM * IDIM + nt * 128;

  int aoff; { int row = t >> 2, jsrc = (t & 3) ^ ((row >> 1) & 3);
              aoff = row * HDIM + jsrc * 8; }
  // bank-even staging map
  const int ks_ = w >> 2, khalf = (w >> 1) & 1, par = w & 1;
  const int dk = (lane >> 1) & 3, h8 = lane & 1;
  const int n16 = (lane >> 3) & 1, n32 = lane >> 4;
  const int bk = 16 * ks_ + 8 * khalf + 4 * par + dk;
  const int bn0 = n32 * 32 + n16 * 16 + h8 * 8;
  const int bgo = bk * IDIM + bn0;             // fp32 source offset (+kb*IDIM)
  const unsigned bwo = (unsigned)(n32 * 1024 + ks_ * 512 + (khalf * 2 + n16) * 128
                                  + par * 64 + dk * 16 + h8 * 8);

  f32x16 ag[2], au[2];
#pragma unroll
  for (int i = 0; i < 2; ++i)
#pragma unroll
    for (int q = 0; q < 16; ++q){ ag[i][q] = 0.f; au[i][q] = 0.f; }

  float4 g0a, g0b, u0a, u0b, g1a, g1b, u1a, u1b;

#define G1_LOAD(KB, RA, RB, RC, RD) {                                          \
    const float* gp_ = gsrc + (size_t)(KB) * IDIM + bgo;                       \
    const float* up_ = usrc + (size_t)(KB) * IDIM + bgo;                       \
    RA = *(const float4*)gp_;       RB = *(const float4*)(gp_ + 4);            \
    RC = *(const float4*)up_;       RD = *(const float4*)(up_ + 4); }

#define G1_STORE(NB, WA, WB, WC, WD) {                                         \
    *(uint4*)&Bs[NB][bwo] = make_uint4(pk2cvt(WA.x,WA.y), pk2cvt(WA.z,WA.w),   \
                                       pk2cvt(WB.x,WB.y), pk2cvt(WB.z,WB.w));  \
    *(uint4*)&Bs[NB][4096 + bwo] = make_uint4(pk2cvt(WC.x,WC.y), pk2cvt(WC.z,WC.w), \
                                       pk2cvt(WD.x,WD.y), pk2cvt(WD.z,WD.w)); }

#define G1_STEP(TI, LA, LB, LC, LD, WA, WB, WC, WD) {                          \
    const int cur_ = (TI) % 3;                                                 \
    const bool pf_ = (TI) + 2 < NK1;                                           \
    if (pf_){                                                                  \
      const int kb2_ = ((TI) + 2) * 32;                                        \
      gload_lds16(abase + aoff + kb2_, &As[((TI) + 2) % 3][w * 64 * 8]);       \
      G1_LOAD(kb2_, LA, LB, LC, LD);                                           \
    }                                                                          \
    const unsigned b0_ = ldsoff(&Bs[cur_][0]) + (unsigned)wc * 2048            \
                         + (unsigned)(lane >> 4) * 256 + (unsigned)(lane & 15) * 8; \
    _Pragma("unroll")                                                          \
    for (int ksi = 0; ksi < 2; ++ksi){                                         \
      bf16x8 af0_, af1_, bg_, bu_;                                             \
      { int row0_ = wr * 64 + (lane & 31);                                     \
        int row1_ = row0_ + 32;                                                \
        int koct_ = ksi * 2 + (lane >> 5);                                     \
        af0_ = *(const bf16x8*)&As[cur_][row0_ * 32 + ((koct_ ^ ((row0_ >> 1) & 3)) * 8)]; \
        af1_ = *(const bf16x8*)&As[cur_][row1_ * 32 + ((koct_ ^ ((row1_ >> 1) & 3)) * 8)]; } \
      { short4v l0_, l1_, m0_, m1_;                                            \
        trread2(b0_ + (unsigned)ksi * 1024, l0_, l1_);                         \
        bg_ = __builtin_shufflevector(l0_, l1_, 0,1,2,3,4,5,6,7);              \
        trread2(b0_ + 8192 + (unsigned)ksi * 1024, m0_, m1_);                  \
        bu_ = __builtin_shufflevector(m0_, m1_, 0,1,2,3,4,5,6,7); }            \
      asm volatile("s_waitcnt lgkmcnt(0)" ::: "memory");                       \
      __builtin_amdgcn_sched_barrier(0);                                       \
      __builtin_amdgcn_s_setprio(1);                                           \
      ag[0] = __builtin_amdgcn_mfma_f32_32x32x16_bf16(af0_, bg_, ag[0], 0, 0, 0); \
      au[0] = __builtin_amdgcn_mfma_f32_32x32x16_bf16(af0_, bu_, au[0], 0, 0, 0); \
      ag[1] = __builtin_amdgcn_mfma_f32_32x32x16_bf16(af1_, bg_, ag[1], 0, 0, 0); \
      au[1] = __builtin_amdgcn_mfma_f32_32x32x16_bf16(af1_, bu_, au[1], 0, 0, 0); \
      __builtin_amdgcn_s_setprio(0);                                           \
    }                                                                          \
    if ((TI) + 1 < NK1){                                                       \
      if (pf_) asm volatile("s_waitcnt vmcnt(5)" ::: "memory");                \
      else     asm volatile("s_waitcnt vmcnt(0)" ::: "memory");                \
      G1_STORE(((TI) + 1) % 3, WA, WB, WC, WD);                                \
    }                                                                          \
    asm volatile("s_waitcnt lgkmcnt(0)" ::: "memory");                         \
    __builtin_amdgcn_s_barrier();                                              \
    __builtin_amdgcn_sched_barrier(0);                                         \
  }

  // prologue: tiles 0,1 in flight (A via gload_lds, B via regs)
  gload_lds16(abase + aoff + 0,  &As[0][w * 64 * 8]);
  G1_LOAD(0,  g0a, g0b, u0a, u0b);
  gload_lds16(abase + aoff + 32, &As[1][w * 64 * 8]);
  G1_LOAD(32, g1a, g1b, u1a, u1b);
  asm volatile("s_waitcnt vmcnt(5)" ::: "memory");   // tile 0 landed
  G1_STORE(0, g0a, g0b, u0a, u0b);
  asm volatile("s_waitcnt lgkmcnt(0)" ::: "memory");
  __builtin_amdgcn_s_barrier();

  for (int tb = 0; tb < NK1; tb += 2){
    G1_STEP(tb,     g0a, g0b, u0a, u0b,  g1a, g1b, u1a, u1b);
    G1_STEP(tb + 1, g1a, g1b, u1a, u1b,  g0a, g0b, u0a, u0b);
  }
#undef G1_STEP
#undef G1_STORE
#undef G1_LOAD

  // epilogue: h = silu(g)*u -> bf16 ; C/D: col=lane&31, row=(r&3)+8(r>>2)+4(l>>5)
#pragma unroll
  for (int mp = 0; mp < 2; ++mp)
#pragma unroll
    for (int r = 0; r < 16; ++r){
      int row = wr * 64 + mp * 32 + (r & 3) + 8 * (r >> 2) + 4 * (lane >> 5);
      int col = nt * 128 + wc * 32 + (lane & 31);
      float gv = ag[mp][r], uv = au[mp][r];
      float hv = gv / (1.f + expf(-gv)) * uv;
      hbuf[(arow0 + row) * IDIM + col] = f2bf(hv);
    }
}

// ---------------- gemm2: eo = h * Wd; 32x32 MFMA -----------------------------
__global__ __launch_bounds__(512, 2) void gemm2_kernel(
    const unsigned short* __restrict__ hbuf,
    const float* __restrict__ wd,
    const int* __restrict__ etot,
    unsigned short* __restrict__ eo)
{
  constexpr int NK2 = IDIM / 32;               // 16 K-steps
  __shared__ unsigned short As[3][128 * 32];
  __shared__ unsigned short Bs[3][2 * 128 * 32];  // [32k][256n] panel, 16 KB
  const int bb = blockIdx.x;
  const int lb = (bb & 7) * 160 + (bb >> 3);   // 1280 blocks
  const int e = lb / 20; const int r2 = lb - e * 20;
  const int nt = r2 / 5, mt = r2 - nt * 5;
  { int cnt = etot[e]; if (cnt > CAPC) cnt = CAPC;
    if (mt * 128 >= cnt) return; }
  const int t = threadIdx.x, w = t >> 6, lane = t & 63;
  const int wr = w >> 2, wc = w & 3;           // wave 64m x 64n
  const size_t arow0 = (size_t)e * CAPC + (size_t)mt * 128;
  const unsigned short* abase = hbuf + arow0 * IDIM;
  const float* dsrc = wd + (size_t)e * IDIM * HDIM + nt * 256;

  int aoff; { int row = t >> 2, jsrc = (t & 3) ^ ((row >> 1) & 3);
              aoff = row * IDIM + jsrc * 8; }
  const int ks_ = w >> 2, khalf = (w >> 1) & 1, par = w & 1;
  const int dk = (lane >> 1) & 3, h8 = lane & 1;
  const int n16 = (lane >> 3) & 1, n32 = lane >> 4;
  const int bk = 16 * ks_ + 8 * khalf + 4 * par + dk;
  const int bn0 = n32 * 32 + n16 * 16 + h8 * 8;       // unit0 ; unit1 at +128
  const int bgo = bk * HDIM + bn0;
  const unsigned bwo = (unsigned)(n32 * 1024 + ks_ * 512 + (khalf * 2 + n16) * 128
                                  + par * 64 + dk * 16 + h8 * 8);

  f32x16 ac[2][2];
#pragma unroll
  for (int i = 0; i < 2; ++i)
#pragma unroll
    for (int j = 0; j < 2; ++j)
#pragma unroll
      for (int q = 0; q < 16; ++q) ac[i][j][q] = 0.f;

  float4 p0a, p0b, p1a, p1b, q0a, q0b, q1a, q1b;

#define G2_LOAD(KB, RA, RB, RC, RD) {                                          \
    const float* gp_ = dsrc + (size_t)(KB) * HDIM + bgo;                       \
    RA = *(const float4*)gp_;         RB = *(const float4*)(gp_ + 4);          \
    RC = *(const float4*)(gp_ + 128); RD = *(const float4*)(gp_ + 132); }

#define G2_STORE(NB, WA, WB, WC, WD) {                                         \
    *(uint4*)&Bs[NB][bwo] = make_uint4(pk2cvt(WA.x,WA.y), pk2cvt(WA.z,WA.w),   \
                                       pk2cvt(WB.x,WB.y), pk2cvt(WB.z,WB.w));  \
    *(uint4*)&Bs[NB][4096 + bwo] = make_uint4(pk2cvt(WC.x,WC.y), pk2cvt(WC.z,WC.w), \
                                       pk2cvt(WD.x,WD.y), pk2cvt(WD.z,WD.w)); }

#define G2_STEP(TI, LA, LB, LC, LD, WA, WB, WC, WD) {                          \
    const int cur_ = (TI) % 3;                                                 \
    const bool pf_ = (TI) + 2 < NK2;                                           \
    if (pf_){                                                                  \
      const int kb2_ = ((TI) + 2) * 32;                                        \
      gload_lds16(abase + aoff + kb2_, &As[((TI) + 2) % 3][w * 64 * 8]);       \
      G2_LOAD(kb2_, LA, LB, LC, LD);                                           \
    }                                                                          \
    const unsigned b0_ = ldsoff(&Bs[cur_][0]) + (unsigned)wc * 4096            \
                         + (unsigned)(lane >> 4) * 256 + (unsigned)(lane & 15) * 8; \
    _Pragma("unroll")                                                          \
    for (int ksi = 0; ksi < 2; ++ksi){                                         \
      bf16x8 af0_, af1_, b0f_, b1f_;                                           \
      { int row0_ = wr * 64 + (lane & 31);                                     \
        int row1_ = row0_ + 32;                                                \
        int koct_ = ksi * 2 + (lane >> 5);                                     \
        af0_ = *(const bf16x8*)&As[cur_][row0_ * 32 + ((koct_ ^ ((row0_ >> 1) & 3)) * 8)]; \
        af1_ = *(const bf16x8*)&As[cur_][row1_ * 32 + ((koct_ ^ ((row1_ >> 1) & 3)) * 8)]; } \
      { short4v l0_, l1_, m0_, m1_;                                            \
        trread2(b0_ + (unsigned)ksi * 1024, l0_, l1_);                         \
        b0f_ = __builtin_shufflevector(l0_, l1_, 0,1,2,3,4,5,6,7);             \
        trread2(b0_ + 2048 + (unsigned)ksi * 1024, m0_, m1_);                  \
        b1f_ = __builtin_shufflevector(m0_, m1_, 0,1,2,3,4,5,6,7); }           \
      asm volatile("s_waitcnt lgkmcnt(0)" ::: "memory");                       \
      __builtin_amdgcn_sched_barrier(0);                                       \
      __builtin_amdgcn_s_setprio(1);                                           \
      ac[0][0] = __builtin_amdgcn_mfma_f32_32x32x16_bf16(af0_, b0f_, ac[0][0], 0, 0, 0); \
      ac[0][1] = __builtin_amdgcn_mfma_f32_32x32x16_bf16(af0_, b1f_, ac[0][1], 0, 0, 0); \
      ac[1][0] = __builtin_amdgcn_mfma_f32_32x32x16_bf16(af1_, b0f_, ac[1][0], 0, 0, 0); \
      ac[1][1] = __builtin_amdgcn_mfma_f32_32x32x16_bf16(af1_, b1f_, ac[1][1], 0, 0, 0); \
      __builtin_amdgcn_s_setprio(0);                                           \
    }                                                                          \
    if ((TI) + 1 < NK2){                                                       \
      if (pf_) asm volatile("s_waitcnt vmcnt(5)" ::: "memory");                \
      else     asm volatile("s_waitcnt vmcnt(0)" ::: "memory");                \
      G2_STORE(((TI) + 1) % 3, WA, WB, WC, WD);                                \
    }                                                                          \
    asm volatile("s_waitcnt lgkmcnt(0)" ::: "memory");                         \
    __builtin_amdgcn_s_barrier();                                              \
    __builtin_amdgcn_sched_barrier(0);                                         \
  }

  gload_lds16(abase + aoff + 0,  &As[0][w * 64 * 8]);
  G2_LOAD(0,  p0a, p0b, q0a, q0b);
  gload_lds16(abase + aoff + 32, &As[1][w * 64 * 8]);
  G2_LOAD(32, p1a, p1b, q1a, q1b);
  asm volatile("s_waitcnt vmcnt(5)" ::: "memory");
  G2_STORE(0, p0a, p0b, q0a, q0b);
  asm volatile("s_waitcnt lgkmcnt(0)" ::: "memory");
  __builtin_amdgcn_s_barrier();

  for (int tb = 0; tb < NK2; tb += 2){
    G2_STEP(tb,     p0a, p0b, q0a, q0b,  p1a, p1b, q1a, q1b);
    G2_STEP(tb + 1, p1a, p1b, q1a, q1b,  p0a, p0b, q0a, q0b);
  }
#undef G2_STEP
#undef G2_STORE
#undef G2_LOAD

#pragma unroll
  for (int mp = 0; mp < 2; ++mp)
#pragma unroll
    for (int np = 0; np < 2; ++np)
#pragma unroll
      for (int r = 0; r < 16; ++r){
        int row = wr * 64 + mp * 32 + (r & 3) + 8 * (r >> 2) + 4 * (lane >> 5);
        int col = nt * 256 + wc * 64 + np * 32 + (lane & 31);
        eo[(arow0 + row) * HDIM + col] = f2bf(ac[mp][np][r]);
      }
}

// ---------------- combine: out[s] = sum_k cw[s,k] * eo[slot(s,k)] ------------
__global__ __launch_bounds__(256) void combine_kernel(
    const unsigned short* __restrict__ eo, const int* __restrict__ entry_slot,
    const float* __restrict__ cw, float* __restrict__ out)
{
  const int s = blockIdx.x, t = threadIdx.x;
  const int s0 = entry_slot[2 * s], s1 = entry_slot[2 * s + 1];
  const float w0 = cw[2 * s], w1 = cw[2 * s + 1];
  const int c = t * 4;
  float r0 = 0.f, r1 = 0.f, r2 = 0.f, r3 = 0.f;
  if (s0 >= 0){
    ushort4 vq = *(const ushort4*)&eo[(size_t)s0 * HDIM + c];
    r0 += w0 * bf2f(vq.x); r1 += w0 * bf2f(vq.y); r2 += w0 * bf2f(vq.z); r3 += w0 * bf2f(vq.w);
  }
  if (s1 >= 0){
    ushort4 vq = *(const ushort4*)&eo[(size_t)s1 * HDIM + c];
    r0 += w1 * bf2f(vq.x); r1 += w1 * bf2f(vq.y); r2 += w1 * bf2f(vq.z); r3 += w1 * bf2f(vq.w);
  }
  ((float4*)(out + (size_t)s * HDIM))[t] = make_float4(r0, r1, r2, r3);
}

extern "C" void kernel_launch(void* const* d_in, const int* in_sizes, int n_in,
                              void* d_out, int out_size, void* d_ws, size_t ws_size,
                              hipStream_t stream) {
  (void)in_sizes; (void)n_in; (void)out_size; (void)ws_size;
  const float* x     = (const float*)d_in[0];
  const float* wgate = (const float*)d_in[1];
  const float* wg    = (const float*)d_in[2];
  const float* wu    = (const float*)d_in[3];
  const float* wd    = (const float*)d_in[4];

  float* out        = (float*)d_out;                         // [S,H]
  float* cw_out     = out + (size_t)S_TOK * HDIM;            // [S,2]
  float* rl_out     = cw_out + (size_t)S_TOK * 2;            // [1]
  float* logits_out = rl_out + 1;                            // [S,64]

  char* w8 = (char*)d_ws;
  size_t off = 0;
  auto alloc = [&](size_t bytes){ size_t r = off; off += (bytes + 255) & ~(size_t)255; return r; };
  int*   flat_e_ws        = (int*)  (w8 + alloc((size_t)32768 * 4));
  float* topk_p_ws        = (float*)(w8 + alloc((size_t)32768 * 4));
  int*   counts_ws        = (int*)  (w8 + alloc((size_t)NCHUNK * NEXP * 4));
  int*   offs_ws          = (int*)  (w8 + alloc((size_t)NCHUNK * NEXP * 4));
  int*   etot_ws          = (int*)  (w8 + alloc((size_t)NEXP * 4));
  int*   entry_slot_ws    = (int*)  (w8 + alloc((size_t)32768 * 4));
  int*   token_of_slot_ws = (int*)  (w8 + alloc((size_t)NEXP * CAPC * 4));
  unsigned short* hbuf_ws = (unsigned short*)(w8 + alloc((size_t)NEXP * CAPC * IDIM * 2));
  unsigned short* adisp_ws= (unsigned short*)(w8 + alloc((size_t)NEXP * CAPC * HDIM * 2));
  unsigned short* eo_ws   = adisp_ws;   // alias: adisp dead after gemm1

  gate_kernel   <<<S_TOK / 4, 256, 0, stream>>>(x, wgate, logits_out, topk_p_ws, flat_e_ws, rl_out);
  hist_kernel   <<<NCHUNK,    256, 0, stream>>>(flat_e_ws, counts_ws);
  offsets_kernel<<<16,        256, 0, stream>>>(counts_ws, offs_ws, etot_ws);
  place_kernel  <<<NCHUNK,    256, 0, stream>>>(flat_e_ws, topk_p_ws, offs_ws,
                                                entry_slot_ws, token_of_slot_ws, cw_out);
  adisp_kernel  <<<NEXP * CAPC, 256, 0, stream>>>(x, token_of_slot_ws, etot_ws, adisp_ws);
  gemm1_kernel  <<<NEXP * 20, 512, 0, stream>>>(adisp_ws, wg, wu, etot_ws, hbuf_ws);
  gemm2_kernel  <<<NEXP * 20, 512, 0, stream>>>(hbuf_ws, wd, etot_ws, eo_ws);
  combine_kernel<<<S_TOK,     256, 0, stream>>>(eo_ws, entry_slot_ws, cw_out, out);
}

// Round 14
// 483.939 us; speedup vs baseline: 1.1880x; 1.0630x over previous
//
// Ernie4.5 MoE MLP — MI355X gfx950
// R14: BM 128->256 in both GEMMs (halves the fp32 B-panel L2 traffic that the
//      R13 arithmetic identified as gemm1's binding cost: 2.4GB -> 1.2GB),
//      partial mt=2 tile guarded (A-row clamp + epilogue write guard).
//      Gate: 4 independent fmaf chains (breaks the 1024-deep latency chain).
//      All R13-verified data contracts unchanged (B subtile/tr_b16, A swizzle,
//      3-buf distance-2 counted-vmcnt (now vmcnt(6): 6 loads/step), cvt_pk).
// ws peak ~121 MB. eo aliases adisp (dead after gemm1).
#include <hip/hip_runtime.h>
#include <hip/hip_bf16.h>

constexpr int S_TOK = 16384;
constexpr int HDIM  = 1024;
constexpr int IDIM  = 512;
constexpr int NEXP  = 64;
constexpr int CAPC  = 640;
constexpr int NCHUNK = 128;   // 32768 routing entries / 256

typedef __attribute__((ext_vector_type(8))) short bf16x8;
typedef __attribute__((ext_vector_type(4))) short short4v;
typedef __attribute__((ext_vector_type(16))) float f32x16;

__device__ __forceinline__ float bf2f(unsigned short u){
  return __uint_as_float(((unsigned)u) << 16);
}
__device__ __forceinline__ unsigned short f2bf(float f){   // RNE bf16 (inputs finite)
  unsigned u = __float_as_uint(f);
  return (unsigned short)((u + 0x7fffu + ((u >> 16) & 1u)) >> 16);
}
// HW packed convert: dst = {lo16: bf16(a), hi16: bf16(b)} (RNE, gfx950)
__device__ __forceinline__ unsigned pk2cvt(float a, float b){
  unsigned r;
  asm volatile("v_cvt_pk_bf16_f32 %0, %1, %2" : "=v"(r) : "v"(a), "v"(b));
  return r;
}
__device__ __forceinline__ void gload_lds16(const void* g, void* l){
  __builtin_amdgcn_global_load_lds((const __attribute__((address_space(1))) unsigned*)g,
                                   (__attribute__((address_space(3))) unsigned*)l, 16, 0, 0);
}
__device__ __forceinline__ unsigned ldsoff(const void* p){ return (unsigned)(size_t)p; }
// two hw-transpose reads: j 0..3 (+0) and j 4..7 (+128B)
__device__ __forceinline__ void trread2(unsigned addr, short4v& lo, short4v& hi){
  asm volatile("ds_read_b64_tr_b16 %0, %2\n\t"
               "ds_read_b64_tr_b16 %1, %2 offset:128"
               : "=&v"(lo), "=&v"(hi) : "v"(addr));
}

// ---------------- gate: logits (fp32 exact), softmax, top-2 -------------------
__global__ __launch_bounds__(256) void gate_kernel(
    const float* __restrict__ x, const float* __restrict__ wgate,
    float* __restrict__ logits_out, float* __restrict__ topk_p,
    int* __restrict__ flat_e, float* __restrict__ rl_out)
{
  __shared__ float xs[4][HDIM];
  const int w = threadIdx.x >> 6, lane = threadIdx.x & 63;
  const int tok = blockIdx.x * 4 + w;
  const float4* xr = (const float4*)(x + (size_t)tok * HDIM);
  float4* xd = (float4*)(&xs[w][0]);
#pragma unroll
  for (int j = 0; j < 4; ++j) xd[j * 64 + lane] = xr[j * 64 + lane];
  __syncthreads();
  // 4 independent chains (breaks 1024-deep fmaf latency chain)
  float a0 = 0.f, a1 = 0.f, a2 = 0.f, a3 = 0.f;
#pragma unroll 4
  for (int h = 0; h < HDIM; h += 4){
    a0 = fmaf(xs[w][h],     wgate[(h)     * NEXP + lane], a0);
    a1 = fmaf(xs[w][h + 1], wgate[(h + 1) * NEXP + lane], a1);
    a2 = fmaf(xs[w][h + 2], wgate[(h + 2) * NEXP + lane], a2);
    a3 = fmaf(xs[w][h + 3], wgate[(h + 3) * NEXP + lane], a3);
  }
  float acc = (a0 + a1) + (a2 + a3);
  logits_out[(size_t)tok * NEXP + lane] = acc;
  float m = acc;
#pragma unroll
  for (int d = 1; d < 64; d <<= 1) m = fmaxf(m, __shfl_xor(m, d));
  float p = expf(acc - m);
  float sum = p;
#pragma unroll
  for (int d = 1; d < 64; d <<= 1) sum += __shfl_xor(sum, d);
  float prob = p / sum;
  float v = prob; int idx = lane;
#pragma unroll
  for (int d = 1; d < 64; d <<= 1){
    float ov = __shfl_xor(v, d); int oi = __shfl_xor(idx, d);
    if (ov > v || (ov == v && oi < idx)){ v = ov; idx = oi; }
  }
  const int e1 = idx; const float p1 = v;
  v = (lane == e1) ? -1.f : prob; idx = lane;
#pragma unroll
  for (int d = 1; d < 64; d <<= 1){
    float ov = __shfl_xor(v, d); int oi = __shfl_xor(idx, d);
    if (ov > v || (ov == v && oi < idx)){ v = ov; idx = oi; }
  }
  if (lane == 0){
    flat_e[tok * 2]     = e1;  flat_e[tok * 2 + 1] = idx;
    topk_p[tok * 2]     = p1;  topk_p[tok * 2 + 1] = v;
  }
  if (tok == 0 && lane == 0) rl_out[0] = 0.f;
}

// ---------------- per-chunk expert histogram ---------------------------------
__global__ __launch_bounds__(256) void hist_kernel(const int* __restrict__ flat_e,
                                                   int* __restrict__ counts)
{
  __shared__ int hh[NEXP];
  const int t = threadIdx.x;
  if (t < NEXP) hh[t] = 0;
  __syncthreads();
  const int e = flat_e[blockIdx.x * 256 + t];
  atomicAdd(&hh[e], 1);
  __syncthreads();
  if (t < NEXP) counts[blockIdx.x * NEXP + t] = hh[t];
}

// ---------------- per-expert exclusive scan over chunks ----------------------
__global__ __launch_bounds__(256) void offsets_kernel(const int* __restrict__ counts,
                                                      int* __restrict__ offs,
                                                      int* __restrict__ etot)
{
  const int w = threadIdx.x >> 6, lane = threadIdx.x & 63;
  const int e = blockIdx.x * 4 + w;
  int v0 = counts[lane * NEXP + e];
  int v1 = counts[(64 + lane) * NEXP + e];
  int s0 = v0, s1 = v1;
#pragma unroll
  for (int d = 1; d < 64; d <<= 1){
    int n0 = __shfl_up(s0, d); if (lane >= d) s0 += n0;
    int n1 = __shfl_up(s1, d); if (lane >= d) s1 += n1;
  }
  const int tot0 = __shfl(s0, 63);
  offs[lane * NEXP + e]        = s0 - v0;
  offs[(64 + lane) * NEXP + e] = tot0 + s1 - v1;
  if (lane == 63) etot[e] = tot0 + s1;
}

// ---------------- ordered placement + slot map + cw --------------------------
__global__ __launch_bounds__(256) void place_kernel(
    const int* __restrict__ flat_e, const float* __restrict__ topk_p,
    const int* __restrict__ offs, int* __restrict__ entry_slot,
    int* __restrict__ token_of_slot, float* __restrict__ cw_out)
{
  __shared__ int es[256];
  __shared__ float wsh[256];
  const int t = threadIdx.x;
  const int i = blockIdx.x * 256 + t;
  const int e = flat_e[i];
  es[t] = e;
  __syncthreads();
  int local = 0;
  for (int j = 0; j < t; ++j) local += (es[j] == e);
  const int pos = offs[blockIdx.x * NEXP + e] + local;
  const bool valid = pos < CAPC;
  const int slot = e * CAPC + pos;
  entry_slot[i] = valid ? slot : -1;
  if (valid) token_of_slot[slot] = i >> 1;
  const float p = topk_p[i];
  wsh[t] = valid ? p : 0.f;
  __syncthreads();
  const float wme = wsh[t], wo = wsh[t ^ 1];
  cw_out[i] = wme / fmaxf(wme + wo, 1e-12f);
}

// ---------------- build dispatched A (bf16) ----------------------------------
__global__ __launch_bounds__(256) void adisp_kernel(
    const float* __restrict__ x, const int* __restrict__ token_of_slot,
    const int* __restrict__ etot, unsigned short* __restrict__ adisp)
{
  const int slot = blockIdx.x;
  const int e = slot / CAPC, c = slot - e * CAPC;
  int cnt = etot[e]; if (cnt > CAPC) cnt = CAPC;
  if (c >= cnt) return;
  const int tok = token_of_slot[slot];
  const int t = threadIdx.x;
  float4 v = ((const float4*)(x + (size_t)tok * HDIM))[t];
  ushort4 o; o.x = f2bf(v.x); o.y = f2bf(v.y); o.z = f2bf(v.z); o.w = f2bf(v.w);
  ((ushort4*)(adisp + (size_t)slot * HDIM))[t] = o;
}

// A tile [256 rows][32 k] bf16: unit c -> row=c>>2, jsrc=(c&3)^((row>>1)&3);
// fragment b128 at row*32 + ((koct ^ ((row>>1)&3))*8). (Verified R4..R13.)
// B panel layout + tr_b16 contract identical to R13 (verified).

// ---------------- gemm1: fused g,u + SwiGLU; 32x32 MFMA; BM=256 --------------
__global__ __launch_bounds__(512) void gemm1_kernel(
    const unsigned short* __restrict__ adisp,
    const float* __restrict__ wg, const float* __restrict__ wu,
    const int* __restrict__ etot,
    unsigned short* __restrict__ hbuf)
{
  constexpr int NK1 = HDIM / 32;               // 32 K-steps
  __shared__ unsigned short As[3][256 * 32];   // 16 KB each
  __shared__ unsigned short Bs[3][2 * 128 * 32]; // panelG + panelU, 16 KB each
  const int bb = blockIdx.x;
  const int lb = (bb & 7) * 96 + (bb >> 3);    // 768 blocks, 768%8==0
  const int e = lb / 12; const int r2 = lb - e * 12;
  const int nt = r2 / 3, mt = r2 - nt * 3;     // mt innermost: 3 share B panel
  { int cnt = etot[e]; if (cnt > CAPC) cnt = CAPC;
    if (mt * 256 >= cnt) return; }             // early-exit empty capacity tiles
  const int t = threadIdx.x, w = t >> 6, lane = t & 63;
  const int wr = w >> 2, wc = w & 3;           // 2m x 4n waves (wave 128m x 32h)
  const size_t arow0 = (size_t)e * CAPC + (size_t)mt * 256;
  const unsigned short* abase = adisp + arow0 * HDIM;
  const float* gsrc = wg + (size_t)e * HDIM * IDIM + nt * 128;
  const float* usrc = wu + (size_t)e * HDIM * IDIM + nt * 128;

  int aoff[2];
#pragma unroll
  for (int rr = 0; rr < 2; ++rr){
    int c = rr * 512 + t;
    int row = c >> 2;
    if (mt * 256 + row >= CAPC) row = 0;       // clamp OOB rows (mt=2 partial)
    int jsrc = (c & 3) ^ ((row >> 1) & 3);
    aoff[rr] = row * HDIM + jsrc * 8;
  }
  // bank-even staging map (R13-verified)
  const int ks_ = w >> 2, khalf = (w >> 1) & 1, par = w & 1;
  const int dk = (lane >> 1) & 3, h8 = lane & 1;
  const int n16 = (lane >> 3) & 1, n32 = lane >> 4;
  const int bk = 16 * ks_ + 8 * khalf + 4 * par + dk;
  const int bn0 = n32 * 32 + n16 * 16 + h8 * 8;
  const int bgo = bk * IDIM + bn0;
  const unsigned bwo = (unsigned)(n32 * 1024 + ks_ * 512 + (khalf * 2 + n16) * 128
                                  + par * 64 + dk * 16 + h8 * 8);

  f32x16 ag[4], au[4];
#pragma unroll
  for (int i = 0; i < 4; ++i)
#pragma unroll
    for (int q = 0; q < 16; ++q){ ag[i][q] = 0.f; au[i][q] = 0.f; }

  float4 g0a, g0b, u0a, u0b, g1a, g1b, u1a, u1b;

#define G1_LOAD(KB, RA, RB, RC, RD) {                                          \
    const float* gp_ = gsrc + (size_t)(KB) * IDIM + bgo;                       \
    const float* up_ = usrc + (size_t)(KB) * IDIM + bgo;                       \
    RA = *(const float4*)gp_;       RB = *(const float4*)(gp_ + 4);            \
    RC = *(const float4*)up_;       RD = *(const float4*)(up_ + 4); }

#define G1_STORE(NB, WA, WB, WC, WD) {                                         \
    *(uint4*)&Bs[NB][bwo] = make_uint4(pk2cvt(WA.x,WA.y), pk2cvt(WA.z,WA.w),   \
                                       pk2cvt(WB.x,WB.y), pk2cvt(WB.z,WB.w));  \
    *(uint4*)&Bs[NB][4096 + bwo] = make_uint4(pk2cvt(WC.x,WC.y), pk2cvt(WC.z,WC.w), \
                                       pk2cvt(WD.x,WD.y), pk2cvt(WD.z,WD.w)); }

#define G1_STEP(TI, LA, LB, LC, LD, WA, WB, WC, WD) {                          \
    const int cur_ = (TI) % 3;                                                 \
    const bool pf_ = (TI) + 2 < NK1;                                           \
    if (pf_){                                                                  \
      const int kb2_ = ((TI) + 2) * 32;                                        \
      gload_lds16(abase + aoff[0] + kb2_, &As[((TI) + 2) % 3][(w * 64) * 8]);  \
      gload_lds16(abase + aoff[1] + kb2_, &As[((TI) + 2) % 3][(512 + w * 64) * 8]); \
      G1_LOAD(kb2_, LA, LB, LC, LD);                                           \
    }                                                                          \
    const unsigned b0_ = ldsoff(&Bs[cur_][0]) + (unsigned)wc * 2048            \
                         + (unsigned)(lane >> 4) * 256 + (unsigned)(lane & 15) * 8; \
    _Pragma("unroll")                                                          \
    for (int ksi = 0; ksi < 2; ++ksi){                                         \
      bf16x8 af_[4], bg_, bu_;                                                 \
      { int koct_ = ksi * 2 + (lane >> 5);                                     \
        _Pragma("unroll")                                                      \
        for (int mp = 0; mp < 4; ++mp){                                        \
          int row_ = wr * 128 + mp * 32 + (lane & 31);                         \
          af_[mp] = *(const bf16x8*)&As[cur_][row_ * 32 + ((koct_ ^ ((row_ >> 1) & 3)) * 8)]; \
        } }                                                                    \
      { short4v l0_, l1_, m0_, m1_;                                            \
        trread2(b0_ + (unsigned)ksi * 1024, l0_, l1_);                         \
        bg_ = __builtin_shufflevector(l0_, l1_, 0,1,2,3,4,5,6,7);              \
        trread2(b0_ + 8192 + (unsigned)ksi * 1024, m0_, m1_);                  \
        bu_ = __builtin_shufflevector(m0_, m1_, 0,1,2,3,4,5,6,7); }            \
      asm volatile("s_waitcnt lgkmcnt(0)" ::: "memory");                       \
      __builtin_amdgcn_sched_barrier(0);                                       \
      __builtin_amdgcn_s_setprio(1);                                           \
      _Pragma("unroll")                                                        \
      for (int mp = 0; mp < 4; ++mp){                                          \
        ag[mp] = __builtin_amdgcn_mfma_f32_32x32x16_bf16(af_[mp], bg_, ag[mp], 0, 0, 0); \
        au[mp] = __builtin_amdgcn_mfma_f32_32x32x16_bf16(af_[mp], bu_, au[mp], 0, 0, 0); \
      }                                                                        \
      __builtin_amdgcn_s_setprio(0);                                           \
    }                                                                          \
    if ((TI) + 1 < NK1){                                                       \
      if (pf_) asm volatile("s_waitcnt vmcnt(6)" ::: "memory");                \
      else     asm volatile("s_waitcnt vmcnt(0)" ::: "memory");                \
      G1_STORE(((TI) + 1) % 3, WA, WB, WC, WD);                                \
    }                                                                          \
    asm volatile("s_waitcnt lgkmcnt(0)" ::: "memory");                         \
    __builtin_amdgcn_s_barrier();                                              \
    __builtin_amdgcn_sched_barrier(0);                                         \
  }

  // prologue: tiles 0,1 in flight (A via gload_lds x2, B via regs)
  gload_lds16(abase + aoff[0] + 0,  &As[0][(w * 64) * 8]);
  gload_lds16(abase + aoff[1] + 0,  &As[0][(512 + w * 64) * 8]);
  G1_LOAD(0,  g0a, g0b, u0a, u0b);
  gload_lds16(abase + aoff[0] + 32, &As[1][(w * 64) * 8]);
  gload_lds16(abase + aoff[1] + 32, &As[1][(512 + w * 64) * 8]);
  G1_LOAD(32, g1a, g1b, u1a, u1b);
  asm volatile("s_waitcnt vmcnt(6)" ::: "memory");   // tile 0 landed
  G1_STORE(0, g0a, g0b, u0a, u0b);
  asm volatile("s_waitcnt lgkmcnt(0)" ::: "memory");
  __builtin_amdgcn_s_barrier();

  for (int tb = 0; tb < NK1; tb += 2){
    G1_STEP(tb,     g0a, g0b, u0a, u0b,  g1a, g1b, u1a, u1b);
    G1_STEP(tb + 1, g1a, g1b, u1a, u1b,  g0a, g0b, u0a, u0b);
  }
#undef G1_STEP
#undef G1_STORE
#undef G1_LOAD

  // epilogue: h = silu(g)*u -> bf16 ; C/D: col=lane&31, row=(r&3)+8(r>>2)+4(l>>5)
#pragma unroll
  for (int mp = 0; mp < 4; ++mp)
#pragma unroll
    for (int r = 0; r < 16; ++r){
      int row = wr * 128 + mp * 32 + (r & 3) + 8 * (r >> 2) + 4 * (lane >> 5);
      if (mt * 256 + row >= CAPC) continue;    // guard partial tile
      int col = nt * 128 + wc * 32 + (lane & 31);
      float gv = ag[mp][r], uv = au[mp][r];
      float hv = gv / (1.f + expf(-gv)) * uv;
      hbuf[(arow0 + row) * IDIM + col] = f2bf(hv);
    }
}

// ---------------- gemm2: eo = h * Wd; 32x32 MFMA; BM=256 ---------------------
__global__ __launch_bounds__(512) void gemm2_kernel(
    const unsigned short* __restrict__ hbuf,
    const float* __restrict__ wd,
    const int* __restrict__ etot,
    unsigned short* __restrict__ eo)
{
  constexpr int NK2 = IDIM / 32;               // 16 K-steps
  __shared__ unsigned short As[3][256 * 32];
  __shared__ unsigned short Bs[3][2 * 128 * 32];  // [32k][256n] panel
  const int bb = blockIdx.x;
  const int lb = (bb & 7) * 96 + (bb >> 3);    // 768 blocks
  const int e = lb / 12; const int r2 = lb - e * 12;
  const int nt = r2 / 3, mt = r2 - nt * 3;
  { int cnt = etot[e]; if (cnt > CAPC) cnt = CAPC;
    if (mt * 256 >= cnt) return; }
  const int t = threadIdx.x, w = t >> 6, lane = t & 63;
  const int wr = w >> 2, wc = w & 3;           // wave 128m x 64n
  const size_t arow0 = (size_t)e * CAPC + (size_t)mt * 256;
  const unsigned short* abase = hbuf + arow0 * IDIM;
  const float* dsrc = wd + (size_t)e * IDIM * HDIM + nt * 256;

  int aoff[2];
#pragma unroll
  for (int rr = 0; rr < 2; ++rr){
    int c = rr * 512 + t;
    int row = c >> 2;
    if (mt * 256 + row >= CAPC) row = 0;
    int jsrc = (c & 3) ^ ((row >> 1) & 3);
    aoff[rr] = row * IDIM + jsrc * 8;
  }
  const int ks_ = w >> 2, khalf = (w >> 1) & 1, par = w & 1;
  const int dk = (lane >> 1) & 3, h8 = lane & 1;
  const int n16 = (lane >> 3) & 1, n32 = lane >> 4;
  const int bk = 16 * ks_ + 8 * khalf + 4 * par + dk;
  const int bn0 = n32 * 32 + n16 * 16 + h8 * 8;       // unit0 ; unit1 at +128
  const int bgo = bk * HDIM + bn0;
  const unsigned bwo = (unsigned)(n32 * 1024 + ks_ * 512 + (khalf * 2 + n16) * 128
                                  + par * 64 + dk * 16 + h8 * 8);

  f32x16 ac[4][2];
#pragma unroll
  for (int i = 0; i < 4; ++i)
#pragma unroll
    for (int j = 0; j < 2; ++j)
#pragma unroll
      for (int q = 0; q < 16; ++q) ac[i][j][q] = 0.f;

  float4 p0a, p0b, p1a, p1b, q0a, q0b, q1a, q1b;

#define G2_LOAD(KB, RA, RB, RC, RD) {                                          \
    const float* gp_ = dsrc + (size_t)(KB) * HDIM + bgo;                       \
    RA = *(const float4*)gp_;         RB = *(const float4*)(gp_ + 4);          \
    RC = *(const float4*)(gp_ + 128); RD = *(const float4*)(gp_ + 132); }

#define G2_STORE(NB, WA, WB, WC, WD) {                                         \
    *(uint4*)&Bs[NB][bwo] = make_uint4(pk2cvt(WA.x,WA.y), pk2cvt(WA.z,WA.w),   \
                                       pk2cvt(WB.x,WB.y), pk2cvt(WB.z,WB.w));  \
    *(uint4*)&Bs[NB][4096 + bwo] = make_uint4(pk2cvt(WC.x,WC.y), pk2cvt(WC.z,WC.w), \
                                       pk2cvt(WD.x,WD.y), pk2cvt(WD.z,WD.w)); }

#define G2_STEP(TI, LA, LB, LC, LD, WA, WB, WC, WD) {                          \
    const int cur_ = (TI) % 3;                                                 \
    const bool pf_ = (TI) + 2 < NK2;                                           \
    if (pf_){                                                                  \
      const int kb2_ = ((TI) + 2) * 32;                                        \
      gload_lds16(abase + aoff[0] + kb2_, &As[((TI) + 2) % 3][(w * 64) * 8]);  \
      gload_lds16(abase + aoff[1] + kb2_, &As[((TI) + 2) % 3][(512 + w * 64) * 8]); \
      G2_LOAD(kb2_, LA, LB, LC, LD);                                           \
    }                                                                          \
    const unsigned b0_ = ldsoff(&Bs[cur_][0]) + (unsigned)wc * 4096            \
                         + (unsigned)(lane >> 4) * 256 + (unsigned)(lane & 15) * 8; \
    _Pragma("unroll")                                                          \
    for (int ksi = 0; ksi < 2; ++ksi){                                         \
      bf16x8 af_[4], b0f_, b1f_;                                               \
      { int koct_ = ksi * 2 + (lane >> 5);                                     \
        _Pragma("unroll")                                                      \
        for (int mp = 0; mp < 4; ++mp){                                        \
          int row_ = wr * 128 + mp * 32 + (lane & 31);                         \
          af_[mp] = *(const bf16x8*)&As[cur_][row_ * 32 + ((koct_ ^ ((row_ >> 1) & 3)) * 8)]; \
        } }                                                                    \
      { short4v l0_, l1_, m0_, m1_;                                            \
        trread2(b0_ + (unsigned)ksi * 1024, l0_, l1_);                         \
        b0f_ = __builtin_shufflevector(l0_, l1_, 0,1,2,3,4,5,6,7);             \
        trread2(b0_ + 2048 + (unsigned)ksi * 1024, m0_, m1_);                  \
        b1f_ = __builtin_shufflevector(m0_, m1_, 0,1,2,3,4,5,6,7); }           \
      asm volatile("s_waitcnt lgkmcnt(0)" ::: "memory");                       \
      __builtin_amdgcn_sched_barrier(0);                                       \
      __builtin_amdgcn_s_setprio(1);                                           \
      _Pragma("unroll")                                                        \
      for (int mp = 0; mp < 4; ++mp){                                          \
        ac[mp][0] = __builtin_amdgcn_mfma_f32_32x32x16_bf16(af_[mp], b0f_, ac[mp][0], 0, 0, 0); \
        ac[mp][1] = __builtin_amdgcn_mfma_f32_32x32x16_bf16(af_[mp], b1f_, ac[mp][1], 0, 0, 0); \
      }                                                                        \
      __builtin_amdgcn_s_setprio(0);                                           \
    }                                                                          \
    if ((TI) + 1 < NK2){                                                       \
      if (pf_) asm volatile("s_waitcnt vmcnt(6)" ::: "memory");                \
      else     asm volatile("s_waitcnt vmcnt(0)" ::: "memory");                \
      G2_STORE(((TI) + 1) % 3, WA, WB, WC, WD);                                \
    }                                                                          \
    asm volatile("s_waitcnt lgkmcnt(0)" ::: "memory");                         \
    __builtin_amdgcn_s_barrier();                                              \
    __builtin_amdgcn_sched_barrier(0);                                         \
  }

  gload_lds16(abase + aoff[0] + 0,  &As[0][(w * 64) * 8]);
  gload_lds16(abase + aoff[1] + 0,  &As[0][(512 + w * 64) * 8]);
  G2_LOAD(0,  p0a, p0b, q0a, q0b);
  gload_lds16(abase + aoff[0] + 32, &As[1][(w * 64) * 8]);
  gload_lds16(abase + aoff[1] + 32, &As[1][(512 + w * 64) * 8]);
  G2_LOAD(32, p1a, p1b, q1a, q1b);
  asm volatile("s_waitcnt vmcnt(6)" ::: "memory");
  G2_STORE(0, p0a, p0b, q0a, q0b);
  asm volatile("s_waitcnt lgkmcnt(0)" ::: "memory");
  __builtin_amdgcn_s_barrier();

  for (int tb = 0; tb < NK2; tb += 2){
    G2_STEP(tb,     p0a, p0b, q0a, q0b,  p1a, p1b, q1a, q1b);
    G2_STEP(tb + 1, p1a, p1b, q1a, q1b,  p0a, p0b, q0a, q0b);
  }
#undef G2_STEP
#undef G2_STORE
#undef G2_LOAD

#pragma unroll
  for (int mp = 0; mp < 4; ++mp)
#pragma unroll
    for (int np = 0; np < 2; ++np)
#pragma unroll
      for (int r = 0; r < 16; ++r){
        int row = wr * 128 + mp * 32 + (r & 3) + 8 * (r >> 2) + 4 * (lane >> 5);
        if (mt * 256 + row >= CAPC) continue;
        int col = nt * 256 + wc * 64 + np * 32 + (lane & 31);
        eo[(arow0 + row) * HDIM + col] = f2bf(ac[mp][np][r]);
      }
}

// ---------------- combine: out[s] = sum_k cw[s,k] * eo[slot(s,k)] ------------
__global__ __launch_bounds__(256) void combine_kernel(
    const unsigned short* __restrict__ eo, const int* __restrict__ entry_slot,
    const float* __restrict__ cw, float* __restrict__ out)
{
  const int s = blockIdx.x, t = threadIdx.x;
  const int s0 = entry_slot[2 * s], s1 = entry_slot[2 * s + 1];
  const float w0 = cw[2 * s], w1 = cw[2 * s + 1];
  const int c = t * 4;
  float r0 = 0.f, r1 = 0.f, r2 = 0.f, r3 = 0.f;
  if (s0 >= 0){
    ushort4 vq = *(const ushort4*)&eo[(size_t)s0 * HDIM + c];
    r0 += w0 * bf2f(vq.x); r1 += w0 * bf2f(vq.y); r2 += w0 * bf2f(vq.z); r3 += w0 * bf2f(vq.w);
  }
  if (s1 >= 0){
    ushort4 vq = *(const ushort4*)&eo[(size_t)s1 * HDIM + c];
    r0 += w1 * bf2f(vq.x); r1 += w1 * bf2f(vq.y); r2 += w1 * bf2f(vq.z); r3 += w1 * bf2f(vq.w);
  }
  ((float4*)(out + (size_t)s * HDIM))[t] = make_float4(r0, r1, r2, r3);
}

extern "C" void kernel_launch(void* const* d_in, const int* in_sizes, int n_in,
                              void* d_out, int out_size, void* d_ws, size_t ws_size,
                              hipStream_t stream) {
  (void)in_sizes; (void)n_in; (void)out_size; (void)ws_size;
  const float* x     = (const float*)d_in[0];
  const float* wgate = (const float*)d_in[1];
  const float* wg    = (const float*)d_in[2];
  const float* wu    = (const float*)d_in[3];
  const float* wd    = (const float*)d_in[4];

  float* out        = (float*)d_out;                         // [S,H]
  float* cw_out     = out + (size_t)S_TOK * HDIM;            // [S,2]
  float* rl_out     = cw_out + (size_t)S_TOK * 2;            // [1]
  float* logits_out = rl_out + 1;                            // [S,64]

  char* w8 = (char*)d_ws;
  size_t off = 0;
  auto alloc = [&](size_t bytes){ size_t r = off; off += (bytes + 255) & ~(size_t)255; return r; };
  int*   flat_e_ws        = (int*)  (w8 + alloc((size_t)32768 * 4));
  float* topk_p_ws        = (float*)(w8 + alloc((size_t)32768 * 4));
  int*   counts_ws        = (int*)  (w8 + alloc((size_t)NCHUNK * NEXP * 4));
  int*   offs_ws          = (int*)  (w8 + alloc((size_t)NCHUNK * NEXP * 4));
  int*   etot_ws          = (int*)  (w8 + alloc((size_t)NEXP * 4));
  int*   entry_slot_ws    = (int*)  (w8 + alloc((size_t)32768 * 4));
  int*   token_of_slot_ws = (int*)  (w8 + alloc((size_t)NEXP * CAPC * 4));
  unsigned short* hbuf_ws = (unsigned short*)(w8 + alloc((size_t)NEXP * CAPC * IDIM * 2));
  unsigned short* adisp_ws= (unsigned short*)(w8 + alloc((size_t)NEXP * CAPC * HDIM * 2));
  unsigned short* eo_ws   = adisp_ws;   // alias: adisp dead after gemm1

  gate_kernel   <<<S_TOK / 4, 256, 0, stream>>>(x, wgate, logits_out, topk_p_ws, flat_e_ws, rl_out);
  hist_kernel   <<<NCHUNK,    256, 0, stream>>>(flat_e_ws, counts_ws);
  offsets_kernel<<<16,        256, 0, stream>>>(counts_ws, offs_ws, etot_ws);
  place_kernel  <<<NCHUNK,    256, 0, stream>>>(flat_e_ws, topk_p_ws, offs_ws,
                                                entry_slot_ws, token_of_slot_ws, cw_out);
  adisp_kernel  <<<NEXP * CAPC, 256, 0, stream>>>(x, token_of_slot_ws, etot_ws, adisp_ws);
  gemm1_kernel  <<<NEXP * 12, 512, 0, stream>>>(adisp_ws, wg, wu, etot_ws, hbuf_ws);
  gemm2_kernel  <<<NEXP * 12, 512, 0, stream>>>(hbuf_ws, wd, etot_ws, eo_ws);
  combine_kernel<<<S_TOK,     256, 0, stream>>>(eo_ws, entry_slot_ws, cw_out, out);
}